// Round 3
// baseline (441.876 us; speedup 1.0000x reference)
//
#include <hip/hip_runtime.h>
#include <math.h>

#define NG 32
#define T_N 40704           // node tile: 40704 floats = 159.0 KB LDS (max 160 KiB)

__device__ __forceinline__ float softplus_f(float x) {
    return (x > 0.f) ? (x + log1pf(expf(-x))) : log1pf(expf(x));
}

// ============== FAST PATH ==============

// K1: per-edge density -> dens_arr; repulsive -> per-graph bins
__global__ __launch_bounds__(256) void k1_edge(
        const float* __restrict__ r, const int* __restrict__ dst,
        const int* __restrict__ n2g,
        const float* __restrict__ p_da, const float* __restrict__ p_dl,
        const float* __restrict__ p_ra, const float* __restrict__ p_rl,
        float* __restrict__ dens_arr, float* __restrict__ e_graph, int E)
{
    __shared__ float sbin[NG];
    if (threadIdx.x < NG) sbin[threadIdx.x] = 0.f;
    __syncthreads();
    const float Ad = softplus_f(*p_da), Ld = softplus_f(*p_dl);
    const float Ar = softplus_f(*p_ra), Lr = softplus_f(*p_rl);
    const float4* r4 = (const float4*)r;
    const int4*   d4 = (const int4*)dst;
    float4* dens4 = (float4*)dens_arr;
    const int NQ = E >> 2;
    const int stride = gridDim.x * blockDim.x;
    for (int q = blockIdx.x*blockDim.x + threadIdx.x; q < NQ; q += stride) {
        float4 a = r4[3*q], b = r4[3*q+1], c = r4[3*q+2];
        int4 dd = d4[q];
        float bl0 = sqrtf(a.x*a.x + a.y*a.y + a.z*a.z);
        float bl1 = sqrtf(a.w*a.w + b.x*b.x + b.y*b.y);
        float bl2 = sqrtf(b.z*b.z + b.w*b.w + c.x*c.x);
        float bl3 = sqrtf(c.y*c.y + c.z*c.z + c.w*c.w);
        float4 dv = { Ad*expf(-Ld*bl0), Ad*expf(-Ld*bl1),
                      Ad*expf(-Ld*bl2), Ad*expf(-Ld*bl3) };
        dens4[q] = dv;
        atomicAdd(&sbin[n2g[dd.x]], Ar*expf(-Lr*bl0));
        atomicAdd(&sbin[n2g[dd.y]], Ar*expf(-Lr*bl1));
        atomicAdd(&sbin[n2g[dd.z]], Ar*expf(-Lr*bl2));
        atomicAdd(&sbin[n2g[dd.w]], Ar*expf(-Lr*bl3));
    }
    for (int e = (NQ<<2) + blockIdx.x*blockDim.x + threadIdx.x; e < E; e += stride) {
        float x = r[3*e], y = r[3*e+1], z = r[3*e+2];
        float bl = sqrtf(x*x + y*y + z*z);
        int de = dst[e];
        dens_arr[e] = Ad*expf(-Ld*bl);
        atomicAdd(&sbin[n2g[de]], Ar*expf(-Lr*bl));
    }
    __syncthreads();
    if (threadIdx.x < NG) atomicAdd(&e_graph[threadIdx.x], sbin[threadIdx.x]);
}

// K2: density scatter into 159KB LDS node tile; flush to scratch (plain stores)
// grid: NT * NC_D blocks; gid = t*NC_D + k
__global__ __launch_bounds__(1024) void k2_dens_tiles(
        const float* __restrict__ dens_arr, const int* __restrict__ dst,
        float* __restrict__ scratch, int E, int NC)
{
    __shared__ float sd[T_N];
    const int t = blockIdx.x / NC, k = blockIdx.x - t*NC;
    const int base = t * T_N;
    for (int i = threadIdx.x; i < T_N; i += blockDim.x) sd[i] = 0.f;
    __syncthreads();
    const int NQ = E >> 2;
    const int cq = (NQ + NC - 1) / NC;
    const int q0 = k*cq;
    const int q1 = (q0 + cq < NQ) ? (q0 + cq) : NQ;
    const float4* dens4 = (const float4*)dens_arr;
    const int4*   d4 = (const int4*)dst;
    for (int q = q0 + (int)threadIdx.x; q < q1; q += (int)blockDim.x) {
        float4 dv = dens4[q]; int4 dd = d4[q];
        unsigned l0 = (unsigned)(dd.x - base); if (l0 < T_N) atomicAdd(&sd[l0], dv.x);
        unsigned l1 = (unsigned)(dd.y - base); if (l1 < T_N) atomicAdd(&sd[l1], dv.y);
        unsigned l2 = (unsigned)(dd.z - base); if (l2 < T_N) atomicAdd(&sd[l2], dv.z);
        unsigned l3 = (unsigned)(dd.w - base); if (l3 < T_N) atomicAdd(&sd[l3], dv.w);
    }
    if (k == NC-1) {
        for (int e = (NQ<<2) + (int)threadIdx.x; e < E; e += (int)blockDim.x) {
            unsigned l = (unsigned)(dst[e] - base);
            if (l < T_N) atomicAdd(&sd[l], dens_arr[e]);
        }
    }
    __syncthreads();
    size_t sb = (size_t)blockIdx.x * T_N;
    for (int i = threadIdx.x; i < T_N; i += blockDim.x) scratch[sb + i] = sd[i];
}

// K3: reduce density chunks; embedding energy -> bins; g = dE/d(local_density)
__global__ __launch_bounds__(256) void k3_node(
        const float* __restrict__ scratch, const int* __restrict__ n2g,
        const float* __restrict__ p_ea,
        float* __restrict__ g_out, float* __restrict__ e_graph, int N, int NC)
{
    __shared__ float sbin[NG];
    if (threadIdx.x < NG) sbin[threadIdx.x] = 0.f;
    __syncthreads();
    const float Ae = softplus_f(*p_ea);
    int n = blockIdx.x*blockDim.x + threadIdx.x;
    if (n < N) {
        int t = n / T_N; int off = n - t*T_N;
        const float* bp = scratch + ((size_t)t*NC)*T_N + off;
        float l = 0.f;
        for (int k = 0; k < NC; ++k) l += bp[(size_t)k*T_N];
        float s = sqrtf(fmaxf(l, 1e-12f));
        atomicAdd(&sbin[n2g[n]], -Ae*s);
        g_out[n] = (l >= 1e-12f) ? (-0.5f*Ae/s) : 0.f;
    }
    __syncthreads();
    if (threadIdx.x < NG) atomicAdd(&e_graph[threadIdx.x], sbin[threadIdx.x]);
}

// K4: per-edge dE/dr, stored SoA: fx[E4], fy[E4], fz[E4] (float4 stores)
__global__ __launch_bounds__(256) void k4_fvec(
        const float* __restrict__ r, const int* __restrict__ dst,
        const float* __restrict__ g,
        const float* __restrict__ p_da, const float* __restrict__ p_dl,
        const float* __restrict__ p_ra, const float* __restrict__ p_rl,
        float* __restrict__ fx, float* __restrict__ fy, float* __restrict__ fz,
        int E)
{
    const float Ad = softplus_f(*p_da), Ld = softplus_f(*p_dl);
    const float Ar = softplus_f(*p_ra), Lr = softplus_f(*p_rl);
    const float4* r4 = (const float4*)r;
    const int4*   d4 = (const int4*)dst;
    float4* fx4 = (float4*)fx; float4* fy4 = (float4*)fy; float4* fz4 = (float4*)fz;
    const int NQ = E >> 2;
    const int stride = gridDim.x * blockDim.x;
    for (int q = blockIdx.x*blockDim.x + threadIdx.x; q < NQ; q += stride) {
        float4 a = r4[3*q], b = r4[3*q+1], c = r4[3*q+2];
        int4 dd = d4[q];
        float bl0 = sqrtf(a.x*a.x + a.y*a.y + a.z*a.z);
        float bl1 = sqrtf(a.w*a.w + b.x*b.x + b.y*b.y);
        float bl2 = sqrtf(b.z*b.z + b.w*b.w + c.x*c.x);
        float bl3 = sqrtf(c.y*c.y + c.z*c.z + c.w*c.w);
        float de0 = g[dd.x]*(-Ld*Ad*expf(-Ld*bl0)) - Lr*Ar*expf(-Lr*bl0);
        float de1 = g[dd.y]*(-Ld*Ad*expf(-Ld*bl1)) - Lr*Ar*expf(-Lr*bl1);
        float de2 = g[dd.z]*(-Ld*Ad*expf(-Ld*bl2)) - Lr*Ar*expf(-Lr*bl2);
        float de3 = g[dd.w]*(-Ld*Ad*expf(-Ld*bl3)) - Lr*Ar*expf(-Lr*bl3);
        float s0 = (bl0 > 0.f) ? de0/bl0 : 0.f;
        float s1 = (bl1 > 0.f) ? de1/bl1 : 0.f;
        float s2 = (bl2 > 0.f) ? de2/bl2 : 0.f;
        float s3 = (bl3 > 0.f) ? de3/bl3 : 0.f;
        float4 vx = { s0*a.x, s1*a.w, s2*b.z, s3*c.y };
        float4 vy = { s0*a.y, s1*b.x, s2*b.w, s3*c.z };
        float4 vz = { s0*a.z, s1*b.y, s2*c.x, s3*c.w };
        fx4[q] = vx; fy4[q] = vy; fz4[q] = vz;
    }
    for (int e = (NQ<<2) + blockIdx.x*blockDim.x + threadIdx.x; e < E; e += stride) {
        float x = r[3*e], y = r[3*e+1], z = r[3*e+2];
        float bl = sqrtf(x*x + y*y + z*z);
        float de = g[dst[e]]*(-Ld*Ad*expf(-Ld*bl)) - Lr*Ar*expf(-Lr*bl);
        float s = (bl > 0.f) ? de/bl : 0.f;
        fx[e] = s*x; fy[e] = s*y; fz[e] = s*z;
    }
}

// K5: component-split force scatter. grid: 3*NT*NC blocks; gid = (c*NT + t)*NC + k
__global__ __launch_bounds__(1024) void k5_comp(
        const float* __restrict__ fsoa,      // fx | fy | fz, each E4 floats
        const int* __restrict__ src, const int* __restrict__ dst,
        float* __restrict__ scratch, int E, int E4, int NT, int NC)
{
    __shared__ float sf[T_N];
    const int gid = blockIdx.x;
    const int k = gid % NC;
    const int ct = gid / NC;
    const int t = ct % NT;
    const int c = ct / NT;
    const int base = t * T_N;
    const float* fcomp = fsoa + (size_t)c * E4;
    for (int i = threadIdx.x; i < T_N; i += blockDim.x) sf[i] = 0.f;
    __syncthreads();
    const int NQ = E >> 2;
    const int cq = (NQ + NC - 1) / NC;
    const int q0 = k*cq;
    const int q1 = (q0 + cq < NQ) ? (q0 + cq) : NQ;
    const float4* f4 = (const float4*)fcomp;
    const int4* d4 = (const int4*)dst;
    const int4* s4 = (const int4*)src;
    for (int q = q0 + (int)threadIdx.x; q < q1; q += (int)blockDim.x) {
        float4 f = f4[q];
        int4 dd = d4[q]; int4 ss = s4[q];
        unsigned l;
        l = (unsigned)(dd.x - base); if (l < T_N) atomicAdd(&sf[l], -f.x);
        l = (unsigned)(ss.x - base); if (l < T_N) atomicAdd(&sf[l],  f.x);
        l = (unsigned)(dd.y - base); if (l < T_N) atomicAdd(&sf[l], -f.y);
        l = (unsigned)(ss.y - base); if (l < T_N) atomicAdd(&sf[l],  f.y);
        l = (unsigned)(dd.z - base); if (l < T_N) atomicAdd(&sf[l], -f.z);
        l = (unsigned)(ss.z - base); if (l < T_N) atomicAdd(&sf[l],  f.z);
        l = (unsigned)(dd.w - base); if (l < T_N) atomicAdd(&sf[l], -f.w);
        l = (unsigned)(ss.w - base); if (l < T_N) atomicAdd(&sf[l],  f.w);
    }
    if (k == NC-1) {
        for (int e = (NQ<<2) + (int)threadIdx.x; e < E; e += (int)blockDim.x) {
            float f = fcomp[e];
            unsigned l;
            l = (unsigned)(dst[e] - base); if (l < T_N) atomicAdd(&sf[l], -f);
            l = (unsigned)(src[e] - base); if (l < T_N) atomicAdd(&sf[l],  f);
        }
    }
    __syncthreads();
    size_t sb = (size_t)gid * T_N;
    for (int i = threadIdx.x; i < T_N; i += blockDim.x) scratch[sb + i] = sf[i];
}

// K6: reduce force chunks -> forces[3n+c] (fully overwrites output)
__global__ __launch_bounds__(256) void k6_force_reduce(
        const float* __restrict__ scratch, float* __restrict__ forces,
        int N, int NT, int NC)
{
    int n = blockIdx.x*blockDim.x + threadIdx.x;
    if (n >= N) return;
    int t = n / T_N; int off = n - t*T_N;
    float out[3];
    #pragma unroll
    for (int c = 0; c < 3; ++c) {
        const float* bp = scratch + ((size_t)(c*NT + t)*NC)*T_N + off;
        float s = 0.f;
        for (int k = 0; k < NC; ++k) s += bp[(size_t)k*T_N];
        out[c] = s;
    }
    forces[3*n+0] = out[0]; forces[3*n+1] = out[1]; forces[3*n+2] = out[2];
}

// ============== FALLBACK PATH (atomic kernels, any ws_size) ==============

__global__ __launch_bounds__(256) void fb_pass1(
        const float* __restrict__ r, const int* __restrict__ dst,
        const int* __restrict__ n2g,
        const float* __restrict__ p_da, const float* __restrict__ p_dl,
        const float* __restrict__ p_ra, const float* __restrict__ p_rl,
        float* __restrict__ local_density, float* __restrict__ e_graph, int E)
{
    __shared__ float sbin[NG];
    if (threadIdx.x < NG) sbin[threadIdx.x] = 0.f;
    __syncthreads();
    const float Ad = softplus_f(*p_da), Ld = softplus_f(*p_dl);
    const float Ar = softplus_f(*p_ra), Lr = softplus_f(*p_rl);
    const int stride = gridDim.x * blockDim.x;
    for (int e = blockIdx.x*blockDim.x + threadIdx.x; e < E; e += stride) {
        float x = r[3*e], y = r[3*e+1], z = r[3*e+2];
        float bl = sqrtf(x*x + y*y + z*z);
        int de = dst[e];
        atomicAdd(&local_density[de], Ad*expf(-Ld*bl));
        atomicAdd(&sbin[n2g[de]], Ar*expf(-Lr*bl));
    }
    __syncthreads();
    if (threadIdx.x < NG) atomicAdd(&e_graph[threadIdx.x], sbin[threadIdx.x]);
}

__global__ __launch_bounds__(256) void fb_pass2(
        float* __restrict__ ld_g, const int* __restrict__ n2g,
        const float* __restrict__ p_ea, float* __restrict__ e_graph, int N)
{
    __shared__ float sbin[NG];
    if (threadIdx.x < NG) sbin[threadIdx.x] = 0.f;
    __syncthreads();
    const float Ae = softplus_f(*p_ea);
    const int stride = gridDim.x * blockDim.x;
    for (int n = blockIdx.x*blockDim.x + threadIdx.x; n < N; n += stride) {
        float l = ld_g[n];
        float s = sqrtf(fmaxf(l, 1e-12f));
        atomicAdd(&sbin[n2g[n]], -Ae*s);
        ld_g[n] = (l >= 1e-12f) ? (-0.5f*Ae/s) : 0.f;
    }
    __syncthreads();
    if (threadIdx.x < NG) atomicAdd(&e_graph[threadIdx.x], sbin[threadIdx.x]);
}

__global__ __launch_bounds__(256) void fb_pass3(
        const float* __restrict__ r, const int* __restrict__ src,
        const int* __restrict__ dst, const float* __restrict__ g,
        const float* __restrict__ p_da, const float* __restrict__ p_dl,
        const float* __restrict__ p_ra, const float* __restrict__ p_rl,
        float* __restrict__ forces, int E)
{
    const float Ad = softplus_f(*p_da), Ld = softplus_f(*p_dl);
    const float Ar = softplus_f(*p_ra), Lr = softplus_f(*p_rl);
    const int stride = gridDim.x * blockDim.x;
    for (int e = blockIdx.x*blockDim.x + threadIdx.x; e < E; e += stride) {
        float x = r[3*e], y = r[3*e+1], z = r[3*e+2];
        float bl = sqrtf(x*x + y*y + z*z);
        int de = dst[e], se = src[e];
        float dEdb = g[de]*(-Ld*Ad*expf(-Ld*bl)) - Lr*Ar*expf(-Lr*bl);
        float s = (bl > 0.f) ? dEdb/bl : 0.f;
        float fx = s*x, fy = s*y, fz = s*z;
        atomicAdd(&forces[3*de+0], -fx); atomicAdd(&forces[3*de+1], -fy); atomicAdd(&forces[3*de+2], -fz);
        atomicAdd(&forces[3*se+0],  fx); atomicAdd(&forces[3*se+1],  fy); atomicAdd(&forces[3*se+2],  fz);
    }
}

extern "C" void kernel_launch(void* const* d_in, const int* in_sizes, int n_in,
                              void* d_out, int out_size, void* d_ws, size_t ws_size,
                              hipStream_t stream) {
    const float* r    = (const float*)d_in[0];
    const int*   src  = (const int*)d_in[1];
    const int*   dst  = (const int*)d_in[2];
    const int*   n2g  = (const int*)d_in[3];
    const float* p_da = (const float*)d_in[4];
    const float* p_dl = (const float*)d_in[5];
    const float* p_ra = (const float*)d_in[6];
    const float* p_rl = (const float*)d_in[7];
    const float* p_ea = (const float*)d_in[8];

    const int E = in_sizes[1];
    const int N = in_sizes[3];

    float* e_graph = (float*)d_out;
    float* forces  = (float*)d_out + NG;

    const int E4 = (E + 3) & ~3;
    const int NT = (N + T_N - 1) / T_N;

    const size_t wsf_n    = ws_size / 4;
    const size_t n_ld     = ((size_t)N + 63) & ~(size_t)63;
    const size_t off_edge = n_ld;
    const size_t off_scr  = off_edge + (size_t)3 * (size_t)E4;

    long avail = (long)wsf_n - (long)off_scr;
    int NC_D = 0, NC_F = 0;
    if (avail > 0) {
        long cd = avail / ((long)NT * T_N);
        long cf = avail / ((long)3 * NT * T_N);
        NC_D = (int)(cd > 84 ? 84 : cd);
        NC_F = (int)(cf > 28 ? 28 : cf);
    }

    const int NQ = E >> 2;
    int ge = (NQ + 255) / 256; if (ge > 2048) ge = 2048;

    if (NC_D >= 1 && NC_F >= 1) {
        float* ld_g    = (float*)d_ws;
        float* edgebuf = (float*)d_ws + off_edge;   // dens[E] then fx|fy|fz (E4 each)
        float* scratch = (float*)d_ws + off_scr;

        hipMemsetAsync(d_out, 0, NG * sizeof(float), stream);

        k1_edge<<<ge, 256, 0, stream>>>(r, dst, n2g, p_da, p_dl, p_ra, p_rl,
                                        edgebuf, e_graph, E);
        k2_dens_tiles<<<NT * NC_D, 1024, 0, stream>>>(edgebuf, dst, scratch, E, NC_D);
        k3_node<<<(N + 255) / 256, 256, 0, stream>>>(scratch, n2g, p_ea,
                                                     ld_g, e_graph, N, NC_D);
        k4_fvec<<<ge, 256, 0, stream>>>(r, dst, ld_g, p_da, p_dl, p_ra, p_rl,
                                        edgebuf, edgebuf + E4, edgebuf + 2*(size_t)E4, E);
        k5_comp<<<3 * NT * NC_F, 1024, 0, stream>>>(edgebuf, src, dst,
                                                    scratch, E, E4, NT, NC_F);
        k6_force_reduce<<<(N + 255) / 256, 256, 0, stream>>>(scratch, forces, N, NT, NC_F);
    } else {
        float* ld_g = (float*)d_ws;
        hipMemsetAsync(d_out, 0, (size_t)out_size * sizeof(float), stream);
        hipMemsetAsync(d_ws, 0, (size_t)N * sizeof(float), stream);
        int geb = (E + 255) / 256; if (geb > 2048) geb = 2048;
        fb_pass1<<<geb, 256, 0, stream>>>(r, dst, n2g, p_da, p_dl, p_ra, p_rl,
                                          ld_g, e_graph, E);
        fb_pass2<<<(N + 255) / 256, 256, 0, stream>>>(ld_g, n2g, p_ea, e_graph, N);
        fb_pass3<<<geb, 256, 0, stream>>>(r, src, dst, ld_g, p_da, p_dl, p_ra, p_rl,
                                          forces, E);
    }
}

// Round 4
// 432.777 us; speedup vs baseline: 1.0210x; 1.0210x over previous
//
#include <hip/hip_runtime.h>
#include <math.h>

#define NG 32
#define T_N 40704           // node tile: 40704 floats = 159.0 KB LDS

__device__ __forceinline__ float softplus_f(float x) {
    return (x > 0.f) ? (x + log1pf(expf(-x))) : log1pf(expf(x));
}

// ============== FAST PATH ==============

// K1: pure streaming map: r -> dens (no index reads)
__global__ __launch_bounds__(256) void k1_dens(
        const float* __restrict__ r,
        const float* __restrict__ p_da, const float* __restrict__ p_dl,
        float* __restrict__ dens_arr, int E)
{
    const float Ad = softplus_f(*p_da), Ld = softplus_f(*p_dl);
    const float4* r4 = (const float4*)r;
    float4* dens4 = (float4*)dens_arr;
    const int NQ = E >> 2;
    const int stride = gridDim.x * blockDim.x;
    for (int q = blockIdx.x*blockDim.x + threadIdx.x; q < NQ; q += stride) {
        float4 a = r4[3*q], b = r4[3*q+1], c = r4[3*q+2];
        float bl0 = sqrtf(a.x*a.x + a.y*a.y + a.z*a.z);
        float bl1 = sqrtf(a.w*a.w + b.x*b.x + b.y*b.y);
        float bl2 = sqrtf(b.z*b.z + b.w*b.w + c.x*c.x);
        float bl3 = sqrtf(c.y*c.y + c.z*c.z + c.w*c.w);
        float4 dv = { Ad*expf(-Ld*bl0), Ad*expf(-Ld*bl1),
                      Ad*expf(-Ld*bl2), Ad*expf(-Ld*bl3) };
        dens4[q] = dv;
    }
    for (int e = (NQ<<2) + blockIdx.x*blockDim.x + threadIdx.x; e < E; e += stride) {
        float x = r[3*e], y = r[3*e+1], z = r[3*e+2];
        float bl = sqrtf(x*x + y*y + z*z);
        dens_arr[e] = Ad*expf(-Ld*bl);
    }
}

__device__ __forceinline__ void dscat(float* sd, int base, int4 dd, float4 dv) {
    unsigned l;
    l = (unsigned)(dd.x - base); if (l < T_N) atomicAdd(&sd[l], dv.x);
    l = (unsigned)(dd.y - base); if (l < T_N) atomicAdd(&sd[l], dv.y);
    l = (unsigned)(dd.z - base); if (l < T_N) atomicAdd(&sd[l], dv.z);
    l = (unsigned)(dd.w - base); if (l < T_N) atomicAdd(&sd[l], dv.w);
}

// K2: density scatter into LDS node tile; 4-quad batches for MLP
__global__ __launch_bounds__(1024, 4) void k2_dens_tiles(
        const float* __restrict__ dens_arr, const int* __restrict__ dst,
        float* __restrict__ scratch, int E, int NC)
{
    __shared__ float sd[T_N];
    const int t = blockIdx.x / NC, k = blockIdx.x - t*NC;
    const int base = t * T_N;
    for (int i = threadIdx.x; i < T_N; i += blockDim.x) sd[i] = 0.f;
    __syncthreads();
    const int NQ = E >> 2;
    const int cq = (NQ + NC - 1) / NC;
    const int q0 = k*cq;
    const int q1 = (q0 + cq < NQ) ? (q0 + cq) : NQ;
    const float4* dens4 = (const float4*)dens_arr;
    const int4*   d4 = (const int4*)dst;
    const int n = q1 - q0;
    const int nmain = n & ~4095;         // multiple of 4*1024
    for (int bqs = q0; bqs < q0 + nmain; bqs += 4096) {
        const int qq = bqs + (int)threadIdx.x*4;
        // issue all 8 loads first (independent) -> deep MLP
        float4 v0 = dens4[qq+0], v1 = dens4[qq+1], v2 = dens4[qq+2], v3 = dens4[qq+3];
        int4   i0 = d4[qq+0],   i1 = d4[qq+1],   i2 = d4[qq+2],   i3 = d4[qq+3];
        dscat(sd, base, i0, v0);
        dscat(sd, base, i1, v1);
        dscat(sd, base, i2, v2);
        dscat(sd, base, i3, v3);
    }
    for (int q = q0 + nmain + (int)threadIdx.x; q < q1; q += 1024) {
        dscat(sd, base, d4[q], dens4[q]);
    }
    if (k == NC-1) {
        for (int e = (NQ<<2) + (int)threadIdx.x; e < E; e += 1024) {
            unsigned l = (unsigned)(dst[e] - base);
            if (l < T_N) atomicAdd(&sd[l], dens_arr[e]);
        }
    }
    __syncthreads();
    size_t sb = (size_t)blockIdx.x * T_N;
    for (int i = threadIdx.x; i < T_N; i += blockDim.x) scratch[sb + i] = sd[i];
}

// K3: reduce density chunks; embedding energy -> bins; g = dE/d(local_density)
__global__ __launch_bounds__(256) void k3_node(
        const float* __restrict__ scratch, const int* __restrict__ n2g,
        const float* __restrict__ p_ea,
        float* __restrict__ g_out, float* __restrict__ e_graph, int N, int NC)
{
    __shared__ float sbin[NG];
    if (threadIdx.x < NG) sbin[threadIdx.x] = 0.f;
    __syncthreads();
    const float Ae = softplus_f(*p_ea);
    int n = blockIdx.x*blockDim.x + threadIdx.x;
    if (n < N) {
        int t = n / T_N; int off = n - t*T_N;
        const float* bp = scratch + ((size_t)t*NC)*T_N + off;
        float l = 0.f;
        for (int k = 0; k < NC; ++k) l += bp[(size_t)k*T_N];
        float s = sqrtf(fmaxf(l, 1e-12f));
        atomicAdd(&sbin[n2g[n]], -Ae*s);
        g_out[n] = (l >= 1e-12f) ? (-0.5f*Ae/s) : 0.f;
    }
    __syncthreads();
    if (threadIdx.x < NG) atomicAdd(&e_graph[threadIdx.x], sbin[threadIdx.x]);
}

// K4: per-edge dE/dr (SoA fx|fy|fz) + repulsive per-graph bins
__global__ __launch_bounds__(256) void k4_fvec(
        const float* __restrict__ r, const int* __restrict__ dst,
        const int* __restrict__ n2g, const float* __restrict__ g,
        const float* __restrict__ p_da, const float* __restrict__ p_dl,
        const float* __restrict__ p_ra, const float* __restrict__ p_rl,
        float* __restrict__ fx, float* __restrict__ fy, float* __restrict__ fz,
        float* __restrict__ e_graph, int E)
{
    __shared__ float sbin[NG];
    if (threadIdx.x < NG) sbin[threadIdx.x] = 0.f;
    __syncthreads();
    const float Ad = softplus_f(*p_da), Ld = softplus_f(*p_dl);
    const float Ar = softplus_f(*p_ra), Lr = softplus_f(*p_rl);
    const float4* r4 = (const float4*)r;
    const int4*   d4 = (const int4*)dst;
    float4* fx4 = (float4*)fx; float4* fy4 = (float4*)fy; float4* fz4 = (float4*)fz;
    const int NQ = E >> 2;
    const int stride = gridDim.x * blockDim.x;
    for (int q = blockIdx.x*blockDim.x + threadIdx.x; q < NQ; q += stride) {
        float4 a = r4[3*q], b = r4[3*q+1], c = r4[3*q+2];
        int4 dd = d4[q];
        float g0 = g[dd.x], g1 = g[dd.y], g2 = g[dd.z], g3 = g[dd.w];
        int b0 = n2g[dd.x], b1 = n2g[dd.y], b2 = n2g[dd.z], b3 = n2g[dd.w];
        float bl0 = sqrtf(a.x*a.x + a.y*a.y + a.z*a.z);
        float bl1 = sqrtf(a.w*a.w + b.x*b.x + b.y*b.y);
        float bl2 = sqrtf(b.z*b.z + b.w*b.w + c.x*c.x);
        float bl3 = sqrtf(c.y*c.y + c.z*c.z + c.w*c.w);
        float rep0 = Ar*expf(-Lr*bl0), rep1 = Ar*expf(-Lr*bl1);
        float rep2 = Ar*expf(-Lr*bl2), rep3 = Ar*expf(-Lr*bl3);
        float de0 = g0*(-Ld*Ad*expf(-Ld*bl0)) - Lr*rep0;
        float de1 = g1*(-Ld*Ad*expf(-Ld*bl1)) - Lr*rep1;
        float de2 = g2*(-Ld*Ad*expf(-Ld*bl2)) - Lr*rep2;
        float de3 = g3*(-Ld*Ad*expf(-Ld*bl3)) - Lr*rep3;
        float s0 = (bl0 > 0.f) ? de0/bl0 : 0.f;
        float s1 = (bl1 > 0.f) ? de1/bl1 : 0.f;
        float s2 = (bl2 > 0.f) ? de2/bl2 : 0.f;
        float s3 = (bl3 > 0.f) ? de3/bl3 : 0.f;
        float4 vx = { s0*a.x, s1*a.w, s2*b.z, s3*c.y };
        float4 vy = { s0*a.y, s1*b.x, s2*b.w, s3*c.z };
        float4 vz = { s0*a.z, s1*b.y, s2*c.x, s3*c.w };
        fx4[q] = vx; fy4[q] = vy; fz4[q] = vz;
        atomicAdd(&sbin[b0], rep0);
        atomicAdd(&sbin[b1], rep1);
        atomicAdd(&sbin[b2], rep2);
        atomicAdd(&sbin[b3], rep3);
    }
    for (int e = (NQ<<2) + blockIdx.x*blockDim.x + threadIdx.x; e < E; e += stride) {
        float x = r[3*e], y = r[3*e+1], z = r[3*e+2];
        float bl = sqrtf(x*x + y*y + z*z);
        int de = dst[e];
        float rep = Ar*expf(-Lr*bl);
        float dEdb = g[de]*(-Ld*Ad*expf(-Ld*bl)) - Lr*rep;
        float s = (bl > 0.f) ? dEdb/bl : 0.f;
        fx[e] = s*x; fy[e] = s*y; fz[e] = s*z;
        atomicAdd(&sbin[n2g[de]], rep);
    }
    __syncthreads();
    if (threadIdx.x < NG) atomicAdd(&e_graph[threadIdx.x], sbin[threadIdx.x]);
}

__device__ __forceinline__ void fscat4(float* sf, int base, int4 dd, int4 ss, float4 f) {
    unsigned l;
    l = (unsigned)(dd.x - base); if (l < T_N) atomicAdd(&sf[l], -f.x);
    l = (unsigned)(ss.x - base); if (l < T_N) atomicAdd(&sf[l],  f.x);
    l = (unsigned)(dd.y - base); if (l < T_N) atomicAdd(&sf[l], -f.y);
    l = (unsigned)(ss.y - base); if (l < T_N) atomicAdd(&sf[l],  f.y);
    l = (unsigned)(dd.z - base); if (l < T_N) atomicAdd(&sf[l], -f.z);
    l = (unsigned)(ss.z - base); if (l < T_N) atomicAdd(&sf[l],  f.z);
    l = (unsigned)(dd.w - base); if (l < T_N) atomicAdd(&sf[l], -f.w);
    l = (unsigned)(ss.w - base); if (l < T_N) atomicAdd(&sf[l],  f.w);
}

// K5: component-split force scatter; 4-quad batches for MLP
// grid: 3*NT*NC blocks; gid = (c*NT + t)*NC + k
__global__ __launch_bounds__(1024, 4) void k5_comp(
        const float* __restrict__ fsoa,      // fx | fy | fz, each E4 floats
        const int* __restrict__ src, const int* __restrict__ dst,
        float* __restrict__ scratch, int E, int E4, int NT, int NC)
{
    __shared__ float sf[T_N];
    const int gid = blockIdx.x;
    const int k = gid % NC;
    const int ct = gid / NC;
    const int t = ct % NT;
    const int c = ct / NT;
    const int base = t * T_N;
    const float* fcomp = fsoa + (size_t)c * E4;
    for (int i = threadIdx.x; i < T_N; i += blockDim.x) sf[i] = 0.f;
    __syncthreads();
    const int NQ = E >> 2;
    const int cq = (NQ + NC - 1) / NC;
    const int q0 = k*cq;
    const int q1 = (q0 + cq < NQ) ? (q0 + cq) : NQ;
    const float4* f4 = (const float4*)fcomp;
    const int4* d4 = (const int4*)dst;
    const int4* s4 = (const int4*)src;
    const int n = q1 - q0;
    const int nmain = n & ~4095;
    for (int bqs = q0; bqs < q0 + nmain; bqs += 4096) {
        const int qq = bqs + (int)threadIdx.x*4;
        // 12 independent loads issued before any atomic
        float4 f0 = f4[qq+0], f1 = f4[qq+1], f2 = f4[qq+2], f3 = f4[qq+3];
        int4  da_ = d4[qq+0], db_ = d4[qq+1], dc_ = d4[qq+2], dd_ = d4[qq+3];
        int4  sa_ = s4[qq+0], sb_ = s4[qq+1], sc_ = s4[qq+2], sd_ = s4[qq+3];
        fscat4(sf, base, da_, sa_, f0);
        fscat4(sf, base, db_, sb_, f1);
        fscat4(sf, base, dc_, sc_, f2);
        fscat4(sf, base, dd_, sd_, f3);
    }
    for (int q = q0 + nmain + (int)threadIdx.x; q < q1; q += 1024) {
        fscat4(sf, base, d4[q], s4[q], f4[q]);
    }
    if (k == NC-1) {
        for (int e = (NQ<<2) + (int)threadIdx.x; e < E; e += 1024) {
            float f = fcomp[e];
            unsigned l;
            l = (unsigned)(dst[e] - base); if (l < T_N) atomicAdd(&sf[l], -f);
            l = (unsigned)(src[e] - base); if (l < T_N) atomicAdd(&sf[l],  f);
        }
    }
    __syncthreads();
    size_t sb = (size_t)gid * T_N;
    for (int i = threadIdx.x; i < T_N; i += blockDim.x) scratch[sb + i] = sf[i];
}

// K6: reduce force chunks -> forces[3n+c] (fully overwrites output)
__global__ __launch_bounds__(256) void k6_force_reduce(
        const float* __restrict__ scratch, float* __restrict__ forces,
        int N, int NT, int NC)
{
    int n = blockIdx.x*blockDim.x + threadIdx.x;
    if (n >= N) return;
    int t = n / T_N; int off = n - t*T_N;
    float out[3];
    #pragma unroll
    for (int c = 0; c < 3; ++c) {
        const float* bp = scratch + ((size_t)(c*NT + t)*NC)*T_N + off;
        float s = 0.f;
        for (int k = 0; k < NC; ++k) s += bp[(size_t)k*T_N];
        out[c] = s;
    }
    forces[3*n+0] = out[0]; forces[3*n+1] = out[1]; forces[3*n+2] = out[2];
}

// ============== FALLBACK PATH (atomic kernels, any ws_size) ==============

__global__ __launch_bounds__(256) void fb_pass1(
        const float* __restrict__ r, const int* __restrict__ dst,
        const int* __restrict__ n2g,
        const float* __restrict__ p_da, const float* __restrict__ p_dl,
        const float* __restrict__ p_ra, const float* __restrict__ p_rl,
        float* __restrict__ local_density, float* __restrict__ e_graph, int E)
{
    __shared__ float sbin[NG];
    if (threadIdx.x < NG) sbin[threadIdx.x] = 0.f;
    __syncthreads();
    const float Ad = softplus_f(*p_da), Ld = softplus_f(*p_dl);
    const float Ar = softplus_f(*p_ra), Lr = softplus_f(*p_rl);
    const int stride = gridDim.x * blockDim.x;
    for (int e = blockIdx.x*blockDim.x + threadIdx.x; e < E; e += stride) {
        float x = r[3*e], y = r[3*e+1], z = r[3*e+2];
        float bl = sqrtf(x*x + y*y + z*z);
        int de = dst[e];
        atomicAdd(&local_density[de], Ad*expf(-Ld*bl));
        atomicAdd(&sbin[n2g[de]], Ar*expf(-Lr*bl));
    }
    __syncthreads();
    if (threadIdx.x < NG) atomicAdd(&e_graph[threadIdx.x], sbin[threadIdx.x]);
}

__global__ __launch_bounds__(256) void fb_pass2(
        float* __restrict__ ld_g, const int* __restrict__ n2g,
        const float* __restrict__ p_ea, float* __restrict__ e_graph, int N)
{
    __shared__ float sbin[NG];
    if (threadIdx.x < NG) sbin[threadIdx.x] = 0.f;
    __syncthreads();
    const float Ae = softplus_f(*p_ea);
    const int stride = gridDim.x * blockDim.x;
    for (int n = blockIdx.x*blockDim.x + threadIdx.x; n < N; n += stride) {
        float l = ld_g[n];
        float s = sqrtf(fmaxf(l, 1e-12f));
        atomicAdd(&sbin[n2g[n]], -Ae*s);
        ld_g[n] = (l >= 1e-12f) ? (-0.5f*Ae/s) : 0.f;
    }
    __syncthreads();
    if (threadIdx.x < NG) atomicAdd(&e_graph[threadIdx.x], sbin[threadIdx.x]);
}

__global__ __launch_bounds__(256) void fb_pass3(
        const float* __restrict__ r, const int* __restrict__ src,
        const int* __restrict__ dst, const float* __restrict__ g,
        const float* __restrict__ p_da, const float* __restrict__ p_dl,
        const float* __restrict__ p_ra, const float* __restrict__ p_rl,
        float* __restrict__ forces, int E)
{
    const float Ad = softplus_f(*p_da), Ld = softplus_f(*p_dl);
    const float Ar = softplus_f(*p_ra), Lr = softplus_f(*p_rl);
    const int stride = gridDim.x * blockDim.x;
    for (int e = blockIdx.x*blockDim.x + threadIdx.x; e < E; e += stride) {
        float x = r[3*e], y = r[3*e+1], z = r[3*e+2];
        float bl = sqrtf(x*x + y*y + z*z);
        int de = dst[e], se = src[e];
        float dEdb = g[de]*(-Ld*Ad*expf(-Ld*bl)) - Lr*Ar*expf(-Lr*bl);
        float s = (bl > 0.f) ? dEdb/bl : 0.f;
        float fx = s*x, fy = s*y, fz = s*z;
        atomicAdd(&forces[3*de+0], -fx); atomicAdd(&forces[3*de+1], -fy); atomicAdd(&forces[3*de+2], -fz);
        atomicAdd(&forces[3*se+0],  fx); atomicAdd(&forces[3*se+1],  fy); atomicAdd(&forces[3*se+2],  fz);
    }
}

extern "C" void kernel_launch(void* const* d_in, const int* in_sizes, int n_in,
                              void* d_out, int out_size, void* d_ws, size_t ws_size,
                              hipStream_t stream) {
    const float* r    = (const float*)d_in[0];
    const int*   src  = (const int*)d_in[1];
    const int*   dst  = (const int*)d_in[2];
    const int*   n2g  = (const int*)d_in[3];
    const float* p_da = (const float*)d_in[4];
    const float* p_dl = (const float*)d_in[5];
    const float* p_ra = (const float*)d_in[6];
    const float* p_rl = (const float*)d_in[7];
    const float* p_ea = (const float*)d_in[8];

    const int E = in_sizes[1];
    const int N = in_sizes[3];

    float* e_graph = (float*)d_out;
    float* forces  = (float*)d_out + NG;

    const int E4 = (E + 3) & ~3;
    const int NT = (N + T_N - 1) / T_N;

    const size_t wsf_n    = ws_size / 4;
    const size_t n_ld     = ((size_t)N + 63) & ~(size_t)63;
    const size_t off_edge = n_ld;
    const size_t off_scr  = off_edge + (size_t)3 * (size_t)E4;

    long avail = (long)wsf_n - (long)off_scr;
    int NC_D = 0, NC_F = 0;
    if (avail > 0) {
        long cd = avail / ((long)NT * T_N);
        long cf = avail / ((long)3 * NT * T_N);
        NC_D = (int)(cd > 84 ? 84 : cd);
        NC_F = (int)(cf > 28 ? 28 : cf);
    }

    const int NQ = E >> 2;
    int ge = (NQ + 255) / 256; if (ge > 2048) ge = 2048;

    if (NC_D >= 1 && NC_F >= 1) {
        float* ld_g    = (float*)d_ws;
        float* edgebuf = (float*)d_ws + off_edge;   // dens[E4] then fx|fy|fz (E4 each)
        float* scratch = (float*)d_ws + off_scr;

        hipMemsetAsync(d_out, 0, NG * sizeof(float), stream);

        k1_dens<<<ge, 256, 0, stream>>>(r, p_da, p_dl, edgebuf, E);
        k2_dens_tiles<<<NT * NC_D, 1024, 0, stream>>>(edgebuf, dst, scratch, E, NC_D);
        k3_node<<<(N + 255) / 256, 256, 0, stream>>>(scratch, n2g, p_ea,
                                                     ld_g, e_graph, N, NC_D);
        k4_fvec<<<ge, 256, 0, stream>>>(r, dst, n2g, ld_g, p_da, p_dl, p_ra, p_rl,
                                        edgebuf, edgebuf + E4, edgebuf + 2*(size_t)E4,
                                        e_graph, E);
        k5_comp<<<3 * NT * NC_F, 1024, 0, stream>>>(edgebuf, src, dst,
                                                    scratch, E, E4, NT, NC_F);
        k6_force_reduce<<<(N + 255) / 256, 256, 0, stream>>>(scratch, forces, N, NT, NC_F);
    } else {
        float* ld_g = (float*)d_ws;
        hipMemsetAsync(d_out, 0, (size_t)out_size * sizeof(float), stream);
        hipMemsetAsync(d_ws, 0, (size_t)N * sizeof(float), stream);
        int geb = (E + 255) / 256; if (geb > 2048) geb = 2048;
        fb_pass1<<<geb, 256, 0, stream>>>(r, dst, n2g, p_da, p_dl, p_ra, p_rl,
                                          ld_g, e_graph, E);
        fb_pass2<<<(N + 255) / 256, 256, 0, stream>>>(ld_g, n2g, p_ea, e_graph, N);
        fb_pass3<<<geb, 256, 0, stream>>>(r, src, dst, ld_g, p_da, p_dl, p_ra, p_rl,
                                          forces, E);
    }
}

// Round 5
// 399.665 us; speedup vs baseline: 1.1056x; 1.0829x over previous
//
#include <hip/hip_runtime.h>
#include <math.h>

#define NG 32
#define T_N 40704           // density tile: 40704 floats = 159.0 KB LDS
#define T_F 13568           // force tile: 13568 nodes * 3 floats = 40704 floats = 159.0 KB
#define T_F3 (T_F*3)

__device__ __forceinline__ float softplus_f(float x) {
    return (x > 0.f) ? (x + log1pf(expf(-x))) : log1pf(expf(x));
}

// gid -> (tile t, chunk c) with all tiles of a chunk on one XCD (gid%8 == c%8),
// assuming round-robin workgroup->XCD dispatch. Requires NC % 8 == 0; else identity.
__device__ __forceinline__ void map_tc(int gid, int NT, int NC, int* t, int* c) {
    if ((NC & 7) == 0) {
        int x = gid & 7, s = gid >> 3;
        *t = s % NT;
        *c = (s / NT) * 8 + x;
    } else {
        *t = gid / NC;
        *c = gid - (*t) * NC;
    }
}

// ============== FAST PATH ==============

// K1: pure streaming map: r -> dens
__global__ __launch_bounds__(256) void k1_dens(
        const float* __restrict__ r,
        const float* __restrict__ p_da, const float* __restrict__ p_dl,
        float* __restrict__ dens_arr, int E)
{
    const float Ad = softplus_f(*p_da), Ld = softplus_f(*p_dl);
    const float4* r4 = (const float4*)r;
    float4* dens4 = (float4*)dens_arr;
    const int NQ = E >> 2;
    const int stride = gridDim.x * blockDim.x;
    for (int q = blockIdx.x*blockDim.x + threadIdx.x; q < NQ; q += stride) {
        float4 a = r4[3*q], b = r4[3*q+1], c = r4[3*q+2];
        float bl0 = sqrtf(a.x*a.x + a.y*a.y + a.z*a.z);
        float bl1 = sqrtf(a.w*a.w + b.x*b.x + b.y*b.y);
        float bl2 = sqrtf(b.z*b.z + b.w*b.w + c.x*c.x);
        float bl3 = sqrtf(c.y*c.y + c.z*c.z + c.w*c.w);
        float4 dv = { Ad*expf(-Ld*bl0), Ad*expf(-Ld*bl1),
                      Ad*expf(-Ld*bl2), Ad*expf(-Ld*bl3) };
        dens4[q] = dv;
    }
    for (int e = (NQ<<2) + blockIdx.x*blockDim.x + threadIdx.x; e < E; e += stride) {
        float x = r[3*e], y = r[3*e+1], z = r[3*e+2];
        float bl = sqrtf(x*x + y*y + z*z);
        dens_arr[e] = Ad*expf(-Ld*bl);
    }
}

// K2: density scatter into 159KB LDS node tile (R2 loop shape, 512 thr)
__global__ __launch_bounds__(512) void k2_dens_tiles(
        const float* __restrict__ dens_arr, const int* __restrict__ dst,
        float* __restrict__ scratch, int E, int NT, int NC)
{
    __shared__ float sd[T_N];
    int t, k;
    map_tc(blockIdx.x, NT, NC, &t, &k);
    const int base = t * T_N;
    for (int i = threadIdx.x; i < T_N; i += blockDim.x) sd[i] = 0.f;
    __syncthreads();
    const int NQ = E >> 2;
    const int cq = (NQ + NC - 1) / NC;
    const int q0 = k*cq;
    const int q1 = (q0 + cq < NQ) ? (q0 + cq) : NQ;
    const float4* dens4 = (const float4*)dens_arr;
    const int4*   d4 = (const int4*)dst;
    for (int q = q0 + (int)threadIdx.x; q < q1; q += (int)blockDim.x) {
        float4 dv = dens4[q]; int4 dd = d4[q];
        unsigned l;
        l = (unsigned)(dd.x - base); if (l < T_N) atomicAdd(&sd[l], dv.x);
        l = (unsigned)(dd.y - base); if (l < T_N) atomicAdd(&sd[l], dv.y);
        l = (unsigned)(dd.z - base); if (l < T_N) atomicAdd(&sd[l], dv.z);
        l = (unsigned)(dd.w - base); if (l < T_N) atomicAdd(&sd[l], dv.w);
    }
    if (k == NC-1) {
        for (int e = (NQ<<2) + (int)threadIdx.x; e < E; e += (int)blockDim.x) {
            unsigned l = (unsigned)(dst[e] - base);
            if (l < T_N) atomicAdd(&sd[l], dens_arr[e]);
        }
    }
    __syncthreads();
    size_t sb = (size_t)(t * NC + k) * T_N;
    for (int i = threadIdx.x; i < T_N; i += blockDim.x) scratch[sb + i] = sd[i];
}

// K3: reduce density chunks; embedding energy -> bins; g = dE/d(local_density)
__global__ __launch_bounds__(256) void k3_node(
        const float* __restrict__ scratch, const int* __restrict__ n2g,
        const float* __restrict__ p_ea,
        float* __restrict__ g_out, float* __restrict__ e_graph, int N, int NC)
{
    __shared__ float sbin[NG];
    if (threadIdx.x < NG) sbin[threadIdx.x] = 0.f;
    __syncthreads();
    const float Ae = softplus_f(*p_ea);
    int n = blockIdx.x*blockDim.x + threadIdx.x;
    if (n < N) {
        int t = n / T_N; int off = n - t*T_N;
        const float* bp = scratch + ((size_t)t*NC)*T_N + off;
        float l = 0.f;
        for (int k = 0; k < NC; ++k) l += bp[(size_t)k*T_N];
        float s = sqrtf(fmaxf(l, 1e-12f));
        atomicAdd(&sbin[n2g[n]], -Ae*s);
        g_out[n] = (l >= 1e-12f) ? (-0.5f*Ae/s) : 0.f;
    }
    __syncthreads();
    if (threadIdx.x < NG) atomicAdd(&e_graph[threadIdx.x], sbin[threadIdx.x]);
}

// K4: per-edge dE/dr (AoS, 3 float4 per quad) + repulsive per-graph bins
__global__ __launch_bounds__(256) void k4_fvec(
        const float* __restrict__ r, const int* __restrict__ dst,
        const int* __restrict__ n2g, const float* __restrict__ g,
        const float* __restrict__ p_da, const float* __restrict__ p_dl,
        const float* __restrict__ p_ra, const float* __restrict__ p_rl,
        float* __restrict__ fvec, float* __restrict__ e_graph, int E)
{
    __shared__ float sbin[NG];
    if (threadIdx.x < NG) sbin[threadIdx.x] = 0.f;
    __syncthreads();
    const float Ad = softplus_f(*p_da), Ld = softplus_f(*p_dl);
    const float Ar = softplus_f(*p_ra), Lr = softplus_f(*p_rl);
    const float4* r4 = (const float4*)r;
    const int4*   d4 = (const int4*)dst;
    float4* f4 = (float4*)fvec;
    const int NQ = E >> 2;
    const int stride = gridDim.x * blockDim.x;
    for (int q = blockIdx.x*blockDim.x + threadIdx.x; q < NQ; q += stride) {
        float4 a = r4[3*q], b = r4[3*q+1], c = r4[3*q+2];
        int4 dd = d4[q];
        float g0 = g[dd.x], g1 = g[dd.y], g2 = g[dd.z], g3 = g[dd.w];
        int b0 = n2g[dd.x], b1 = n2g[dd.y], b2 = n2g[dd.z], b3 = n2g[dd.w];
        float bl0 = sqrtf(a.x*a.x + a.y*a.y + a.z*a.z);
        float bl1 = sqrtf(a.w*a.w + b.x*b.x + b.y*b.y);
        float bl2 = sqrtf(b.z*b.z + b.w*b.w + c.x*c.x);
        float bl3 = sqrtf(c.y*c.y + c.z*c.z + c.w*c.w);
        float rep0 = Ar*expf(-Lr*bl0), rep1 = Ar*expf(-Lr*bl1);
        float rep2 = Ar*expf(-Lr*bl2), rep3 = Ar*expf(-Lr*bl3);
        float de0 = g0*(-Ld*Ad*expf(-Ld*bl0)) - Lr*rep0;
        float de1 = g1*(-Ld*Ad*expf(-Ld*bl1)) - Lr*rep1;
        float de2 = g2*(-Ld*Ad*expf(-Ld*bl2)) - Lr*rep2;
        float de3 = g3*(-Ld*Ad*expf(-Ld*bl3)) - Lr*rep3;
        float s0 = (bl0 > 0.f) ? de0/bl0 : 0.f;
        float s1 = (bl1 > 0.f) ? de1/bl1 : 0.f;
        float s2 = (bl2 > 0.f) ? de2/bl2 : 0.f;
        float s3 = (bl3 > 0.f) ? de3/bl3 : 0.f;
        float4 o0 = { s0*a.x, s0*a.y, s0*a.z, s1*a.w };
        float4 o1 = { s1*b.x, s1*b.y, s2*b.z, s2*b.w };
        float4 o2 = { s2*c.x, s3*c.y, s3*c.z, s3*c.w };
        f4[3*q] = o0; f4[3*q+1] = o1; f4[3*q+2] = o2;
        atomicAdd(&sbin[b0], rep0);
        atomicAdd(&sbin[b1], rep1);
        atomicAdd(&sbin[b2], rep2);
        atomicAdd(&sbin[b3], rep3);
    }
    for (int e = (NQ<<2) + blockIdx.x*blockDim.x + threadIdx.x; e < E; e += stride) {
        float x = r[3*e], y = r[3*e+1], z = r[3*e+2];
        float bl = sqrtf(x*x + y*y + z*z);
        int de = dst[e];
        float rep = Ar*expf(-Lr*bl);
        float dEdb = g[de]*(-Ld*Ad*expf(-Ld*bl)) - Lr*rep;
        float s = (bl > 0.f) ? dEdb/bl : 0.f;
        fvec[3*e] = s*x; fvec[3*e+1] = s*y; fvec[3*e+2] = s*z;
        atomicAdd(&sbin[n2g[de]], rep);
    }
    __syncthreads();
    if (threadIdx.x < NG) atomicAdd(&e_graph[threadIdx.x], sbin[threadIdx.x]);
}

__device__ __forceinline__ void fscat(float* sf, int base, int d, int s,
                                      float fx, float fy, float fz) {
    unsigned ld = (unsigned)(d - base);
    if (ld < T_F) {
        atomicAdd(&sf[3*ld+0], -fx); atomicAdd(&sf[3*ld+1], -fy); atomicAdd(&sf[3*ld+2], -fz);
    }
    unsigned ls = (unsigned)(s - base);
    if (ls < T_F) {
        atomicAdd(&sf[3*ls+0],  fx); atomicAdd(&sf[3*ls+1],  fy); atomicAdd(&sf[3*ls+2],  fz);
    }
}

// K5: force scatter, R2 loop shape (512 thr, AoS fvec), 159KB LDS tile
__global__ __launch_bounds__(512) void k5_force_tiles(
        const float* __restrict__ fvec, const int* __restrict__ src,
        const int* __restrict__ dst,
        float* __restrict__ scratch, int E, int NT, int NC)
{
    __shared__ float sf[T_F3];
    int t, c;
    map_tc(blockIdx.x, NT, NC, &t, &c);
    const int base = t * T_F;
    for (int i = threadIdx.x; i < T_F3; i += blockDim.x) sf[i] = 0.f;
    __syncthreads();
    const int NQ = E >> 2;
    const int cq = (NQ + NC - 1) / NC;
    const int q0 = c*cq;
    const int q1 = (q0 + cq < NQ) ? (q0 + cq) : NQ;
    const float4* f4 = (const float4*)fvec;
    const int4* d4 = (const int4*)dst;
    const int4* s4 = (const int4*)src;
    for (int q = q0 + (int)threadIdx.x; q < q1; q += (int)blockDim.x) {
        float4 a = f4[3*q], b = f4[3*q+1], cc = f4[3*q+2];
        int4 dd = d4[q]; int4 ss = s4[q];
        fscat(sf, base, dd.x, ss.x, a.x,  a.y,  a.z);
        fscat(sf, base, dd.y, ss.y, a.w,  b.x,  b.y);
        fscat(sf, base, dd.z, ss.z, b.z,  b.w,  cc.x);
        fscat(sf, base, dd.w, ss.w, cc.y, cc.z, cc.w);
    }
    if (c == NC-1) {
        for (int e = (NQ<<2) + (int)threadIdx.x; e < E; e += (int)blockDim.x) {
            fscat(sf, base, dst[e], src[e], fvec[3*e], fvec[3*e+1], fvec[3*e+2]);
        }
    }
    __syncthreads();
    size_t sb = (size_t)(t * NC + c) * T_F3;
    for (int i = threadIdx.x; i < T_F3; i += blockDim.x) scratch[sb + i] = sf[i];
}

// K6: reduce force chunks -> forces (fully overwrites output)
__global__ __launch_bounds__(256) void k6_force_reduce(
        const float* __restrict__ scratch, float* __restrict__ forces,
        int N, int NC)
{
    int n = blockIdx.x*blockDim.x + threadIdx.x;
    if (n >= N) return;
    int t = n / T_F; int off = n - t*T_F;
    const float* bp = scratch + ((size_t)t*NC)*T_F3 + 3*off;
    float ox = 0.f, oy = 0.f, oz = 0.f;
    for (int k = 0; k < NC; ++k) {
        const float* p = bp + (size_t)k*T_F3;
        ox += p[0]; oy += p[1]; oz += p[2];
    }
    forces[3*n+0] = ox; forces[3*n+1] = oy; forces[3*n+2] = oz;
}

// ============== FALLBACK PATH (atomic kernels, any ws_size) ==============

__global__ __launch_bounds__(256) void fb_pass1(
        const float* __restrict__ r, const int* __restrict__ dst,
        const int* __restrict__ n2g,
        const float* __restrict__ p_da, const float* __restrict__ p_dl,
        const float* __restrict__ p_ra, const float* __restrict__ p_rl,
        float* __restrict__ local_density, float* __restrict__ e_graph, int E)
{
    __shared__ float sbin[NG];
    if (threadIdx.x < NG) sbin[threadIdx.x] = 0.f;
    __syncthreads();
    const float Ad = softplus_f(*p_da), Ld = softplus_f(*p_dl);
    const float Ar = softplus_f(*p_ra), Lr = softplus_f(*p_rl);
    const int stride = gridDim.x * blockDim.x;
    for (int e = blockIdx.x*blockDim.x + threadIdx.x; e < E; e += stride) {
        float x = r[3*e], y = r[3*e+1], z = r[3*e+2];
        float bl = sqrtf(x*x + y*y + z*z);
        int de = dst[e];
        atomicAdd(&local_density[de], Ad*expf(-Ld*bl));
        atomicAdd(&sbin[n2g[de]], Ar*expf(-Lr*bl));
    }
    __syncthreads();
    if (threadIdx.x < NG) atomicAdd(&e_graph[threadIdx.x], sbin[threadIdx.x]);
}

__global__ __launch_bounds__(256) void fb_pass2(
        float* __restrict__ ld_g, const int* __restrict__ n2g,
        const float* __restrict__ p_ea, float* __restrict__ e_graph, int N)
{
    __shared__ float sbin[NG];
    if (threadIdx.x < NG) sbin[threadIdx.x] = 0.f;
    __syncthreads();
    const float Ae = softplus_f(*p_ea);
    const int stride = gridDim.x * blockDim.x;
    for (int n = blockIdx.x*blockDim.x + threadIdx.x; n < N; n += stride) {
        float l = ld_g[n];
        float s = sqrtf(fmaxf(l, 1e-12f));
        atomicAdd(&sbin[n2g[n]], -Ae*s);
        ld_g[n] = (l >= 1e-12f) ? (-0.5f*Ae/s) : 0.f;
    }
    __syncthreads();
    if (threadIdx.x < NG) atomicAdd(&e_graph[threadIdx.x], sbin[threadIdx.x]);
}

__global__ __launch_bounds__(256) void fb_pass3(
        const float* __restrict__ r, const int* __restrict__ src,
        const int* __restrict__ dst, const float* __restrict__ g,
        const float* __restrict__ p_da, const float* __restrict__ p_dl,
        const float* __restrict__ p_ra, const float* __restrict__ p_rl,
        float* __restrict__ forces, int E)
{
    const float Ad = softplus_f(*p_da), Ld = softplus_f(*p_dl);
    const float Ar = softplus_f(*p_ra), Lr = softplus_f(*p_rl);
    const int stride = gridDim.x * blockDim.x;
    for (int e = blockIdx.x*blockDim.x + threadIdx.x; e < E; e += stride) {
        float x = r[3*e], y = r[3*e+1], z = r[3*e+2];
        float bl = sqrtf(x*x + y*y + z*z);
        int de = dst[e], se = src[e];
        float dEdb = g[de]*(-Ld*Ad*expf(-Ld*bl)) - Lr*Ar*expf(-Lr*bl);
        float s = (bl > 0.f) ? dEdb/bl : 0.f;
        float fx = s*x, fy = s*y, fz = s*z;
        atomicAdd(&forces[3*de+0], -fx); atomicAdd(&forces[3*de+1], -fy); atomicAdd(&forces[3*de+2], -fz);
        atomicAdd(&forces[3*se+0],  fx); atomicAdd(&forces[3*se+1],  fy); atomicAdd(&forces[3*se+2],  fz);
    }
}

extern "C" void kernel_launch(void* const* d_in, const int* in_sizes, int n_in,
                              void* d_out, int out_size, void* d_ws, size_t ws_size,
                              hipStream_t stream) {
    const float* r    = (const float*)d_in[0];
    const int*   src  = (const int*)d_in[1];
    const int*   dst  = (const int*)d_in[2];
    const int*   n2g  = (const int*)d_in[3];
    const float* p_da = (const float*)d_in[4];
    const float* p_dl = (const float*)d_in[5];
    const float* p_ra = (const float*)d_in[6];
    const float* p_rl = (const float*)d_in[7];
    const float* p_ea = (const float*)d_in[8];

    const int E = in_sizes[1];
    const int N = in_sizes[3];

    float* e_graph = (float*)d_out;
    float* forces  = (float*)d_out + NG;

    const int E4 = (E + 3) & ~3;
    const int NT_D = (N + T_N - 1) / T_N;   // 3
    const int NT_F = (N + T_F - 1) / T_F;   // 8

    const size_t wsf_n    = ws_size / 4;
    const size_t n_ld     = ((size_t)N + 63) & ~(size_t)63;
    const size_t off_edge = n_ld;
    const size_t off_scr  = off_edge + (size_t)3 * (size_t)E4;

    long avail = (long)wsf_n - (long)off_scr;
    int NC_D = 0, NC_F = 0;
    if (avail > 0) {
        long cd = avail / ((long)NT_D * T_N);
        long cf = avail / ((long)NT_F * T_F3);
        NC_D = (int)(cd > 80 ? 80 : cd);
        NC_F = (int)(cf > 32 ? 32 : cf);
        // prefer multiples of 8 for the XCD-grouped mapping
        if (NC_D >= 8) NC_D &= ~7;
        if (NC_F >= 8) NC_F &= ~7;
    }

    const int NQ = E >> 2;
    int ge = (NQ + 255) / 256; if (ge > 2048) ge = 2048;

    if (NC_D >= 1 && NC_F >= 1) {
        float* ld_g    = (float*)d_ws;
        float* edgebuf = (float*)d_ws + off_edge;   // dens[E4], then fvec[3E] AoS
        float* scratch = (float*)d_ws + off_scr;

        hipMemsetAsync(d_out, 0, NG * sizeof(float), stream);

        k1_dens<<<ge, 256, 0, stream>>>(r, p_da, p_dl, edgebuf, E);
        k2_dens_tiles<<<NT_D * NC_D, 512, 0, stream>>>(edgebuf, dst, scratch,
                                                       E, NT_D, NC_D);
        k3_node<<<(N + 255) / 256, 256, 0, stream>>>(scratch, n2g, p_ea,
                                                     ld_g, e_graph, N, NC_D);
        k4_fvec<<<ge, 256, 0, stream>>>(r, dst, n2g, ld_g, p_da, p_dl, p_ra, p_rl,
                                        edgebuf, e_graph, E);
        k5_force_tiles<<<NT_F * NC_F, 512, 0, stream>>>(edgebuf, src, dst,
                                                        scratch, E, NT_F, NC_F);
        k6_force_reduce<<<(N + 255) / 256, 256, 0, stream>>>(scratch, forces, N, NC_F);
    } else {
        float* ld_g = (float*)d_ws;
        hipMemsetAsync(d_out, 0, (size_t)out_size * sizeof(float), stream);
        hipMemsetAsync(d_ws, 0, (size_t)N * sizeof(float), stream);
        int geb = (E + 255) / 256; if (geb > 2048) geb = 2048;
        fb_pass1<<<geb, 256, 0, stream>>>(r, dst, n2g, p_da, p_dl, p_ra, p_rl,
                                          ld_g, e_graph, E);
        fb_pass2<<<(N + 255) / 256, 256, 0, stream>>>(ld_g, n2g, p_ea, e_graph, N);
        fb_pass3<<<geb, 256, 0, stream>>>(r, src, dst, ld_g, p_da, p_dl, p_ra, p_rl,
                                          forces, E);
    }
}

// Round 6
// 399.258 us; speedup vs baseline: 1.1067x; 1.0010x over previous
//
#include <hip/hip_runtime.h>
#include <math.h>

#define NG 32

#if defined(__has_builtin)
#  if __has_builtin(__builtin_amdgcn_ds_atomic_fadd_v2f32)
#    define HAS_PK_LDS 1
#  endif
#endif

__device__ __forceinline__ float softplus_f(float x) {
    return (x > 0.f) ? (x + log1pf(expf(-x))) : log1pf(expf(x));
}

// gid -> (tile t, chunk c) with all tiles of a chunk on one XCD (gid%8 == c%8),
// assuming round-robin workgroup->XCD dispatch. Requires NC % 8 == 0; else identity.
__device__ __forceinline__ void map_tc(int gid, int NT, int NC, int* t, int* c) {
    if ((NC & 7) == 0) {
        int x = gid & 7, s = gid >> 3;
        *t = s % NT;
        *c = (s / NT) * 8 + x;
    } else {
        *t = gid / NC;
        *c = gid - (*t) * NC;
    }
}

// K1: pure streaming map: r -> dens  (shared by both paths)
__global__ __launch_bounds__(256) void k1_dens(
        const float* __restrict__ r,
        const float* __restrict__ p_da, const float* __restrict__ p_dl,
        float* __restrict__ dens_arr, int E)
{
    const float Ad = softplus_f(*p_da), Ld = softplus_f(*p_dl);
    const float4* r4 = (const float4*)r;
    float4* dens4 = (float4*)dens_arr;
    const int NQ = E >> 2;
    const int stride = gridDim.x * blockDim.x;
    for (int q = blockIdx.x*blockDim.x + threadIdx.x; q < NQ; q += stride) {
        float4 a = r4[3*q], b = r4[3*q+1], c = r4[3*q+2];
        float bl0 = sqrtf(a.x*a.x + a.y*a.y + a.z*a.z);
        float bl1 = sqrtf(a.w*a.w + b.x*b.x + b.y*b.y);
        float bl2 = sqrtf(b.z*b.z + b.w*b.w + c.x*c.x);
        float bl3 = sqrtf(c.y*c.y + c.z*c.z + c.w*c.w);
        float4 dv = { Ad*expf(-Ld*bl0), Ad*expf(-Ld*bl1),
                      Ad*expf(-Ld*bl2), Ad*expf(-Ld*bl3) };
        dens4[q] = dv;
    }
    for (int e = (NQ<<2) + blockIdx.x*blockDim.x + threadIdx.x; e < E; e += stride) {
        float x = r[3*e], y = r[3*e+1], z = r[3*e+2];
        float bl = sqrtf(x*x + y*y + z*z);
        dens_arr[e] = Ad*expf(-Ld*bl);
    }
}

#ifdef HAS_PK_LDS
// =================== PK PATH ===================
#define T_A 20352           // (dens,rep) pairs/node: 20352*2 floats = 159.0 KB
#define T_C 10176           // force nodes: 10176*4 floats = 159.0 KB

typedef float v2f __attribute__((ext_vector_type(2)));
typedef __attribute__((address_space(3))) v2f* lds_v2f_ptr;

__device__ __forceinline__ void pk_add(float* p, float a, float b) {
    v2f v; v.x = a; v.y = b;
    (void)__builtin_amdgcn_ds_atomic_fadd_v2f32((lds_v2f_ptr)p, v);
}

// K2: scatter (dens, rep) pair per edge onto dst node tile; 1 pk-atomic per taken edge
__global__ __launch_bounds__(512) void k2_pk(
        const float* __restrict__ dens_arr, const int* __restrict__ dst,
        const float* __restrict__ p_da, const float* __restrict__ p_dl,
        const float* __restrict__ p_ra, const float* __restrict__ p_rl,
        float* __restrict__ scratch, int E, int NT, int NC)
{
    __shared__ __align__(16) float sd[T_A*2];
    int t, k;
    map_tc(blockIdx.x, NT, NC, &t, &k);
    const int base = t * T_A;
    for (int i = threadIdx.x; i < T_A*2; i += blockDim.x) sd[i] = 0.f;
    __syncthreads();
    const float Ad = softplus_f(*p_da), Ld = softplus_f(*p_dl);
    const float Ar = softplus_f(*p_ra), Lr = softplus_f(*p_rl);
    const float pw = Lr / Ld;        // rep = Ar * (dens/Ad)^(Lr/Ld)
    const float invAd = 1.f / Ad;
    const int NQ = E >> 2;
    const int cq = (NQ + NC - 1) / NC;
    const int q0 = k*cq;
    const int q1 = (q0 + cq < NQ) ? (q0 + cq) : NQ;
    const float4* dens4 = (const float4*)dens_arr;
    const int4*   d4 = (const int4*)dst;
    for (int q = q0 + (int)threadIdx.x; q < q1; q += (int)blockDim.x) {
        float4 dv = dens4[q]; int4 dd = d4[q];
        float r0 = Ar*expf(pw*logf(dv.x*invAd));
        float r1 = Ar*expf(pw*logf(dv.y*invAd));
        float r2 = Ar*expf(pw*logf(dv.z*invAd));
        float r3 = Ar*expf(pw*logf(dv.w*invAd));
        unsigned l;
        l = (unsigned)(dd.x - base); if (l < T_A) pk_add(&sd[2*l], dv.x, r0);
        l = (unsigned)(dd.y - base); if (l < T_A) pk_add(&sd[2*l], dv.y, r1);
        l = (unsigned)(dd.z - base); if (l < T_A) pk_add(&sd[2*l], dv.z, r2);
        l = (unsigned)(dd.w - base); if (l < T_A) pk_add(&sd[2*l], dv.w, r3);
    }
    if (k == NC-1) {
        for (int e = (NQ<<2) + (int)threadIdx.x; e < E; e += (int)blockDim.x) {
            float dv = dens_arr[e];
            float rp = Ar*expf(pw*logf(dv*invAd));
            unsigned l = (unsigned)(dst[e] - base);
            if (l < T_A) pk_add(&sd[2*l], dv, rp);
        }
    }
    __syncthreads();
    size_t sb = (size_t)(t * NC + k) * (T_A*2);
    for (int i = threadIdx.x; i < T_A*2; i += blockDim.x) scratch[sb + i] = sd[i];
}

// K3: reduce (dens,rep) chunks; e_graph += F + rep_node; g = dE/d(local_density)
__global__ __launch_bounds__(256) void k3_pk(
        const float* __restrict__ scratch, const int* __restrict__ n2g,
        const float* __restrict__ p_ea,
        float* __restrict__ g_out, float* __restrict__ e_graph, int N, int NC)
{
    __shared__ float sbin[NG];
    if (threadIdx.x < NG) sbin[threadIdx.x] = 0.f;
    __syncthreads();
    const float Ae = softplus_f(*p_ea);
    int n = blockIdx.x*blockDim.x + threadIdx.x;
    if (n < N) {
        int t = n / T_A; int off = n - t*T_A;
        const float2* sp = (const float2*)scratch;
        size_t idx0 = (size_t)(t*NC)*T_A + off;
        float l = 0.f, rp = 0.f;
        for (int k = 0; k < NC; ++k) {
            float2 v = sp[idx0 + (size_t)k*T_A];
            l += v.x; rp += v.y;
        }
        float s = sqrtf(fmaxf(l, 1e-12f));
        atomicAdd(&sbin[n2g[n]], rp - Ae*s);
        g_out[n] = (l >= 1e-12f) ? (-0.5f*Ae/s) : 0.f;
    }
    __syncthreads();
    if (threadIdx.x < NG) atomicAdd(&e_graph[threadIdx.x], sbin[threadIdx.x]);
}

// K4: per-edge dE/dr (AoS, 3 float4 per quad); no bins
__global__ __launch_bounds__(256) void k4_pk(
        const float* __restrict__ r, const int* __restrict__ dst,
        const float* __restrict__ g,
        const float* __restrict__ p_da, const float* __restrict__ p_dl,
        const float* __restrict__ p_ra, const float* __restrict__ p_rl,
        float* __restrict__ fvec, int E)
{
    const float Ad = softplus_f(*p_da), Ld = softplus_f(*p_dl);
    const float Ar = softplus_f(*p_ra), Lr = softplus_f(*p_rl);
    const float4* r4 = (const float4*)r;
    const int4*   d4 = (const int4*)dst;
    float4* f4 = (float4*)fvec;
    const int NQ = E >> 2;
    const int stride = gridDim.x * blockDim.x;
    for (int q = blockIdx.x*blockDim.x + threadIdx.x; q < NQ; q += stride) {
        float4 a = r4[3*q], b = r4[3*q+1], c = r4[3*q+2];
        int4 dd = d4[q];
        float g0 = g[dd.x], g1 = g[dd.y], g2 = g[dd.z], g3 = g[dd.w];
        float bl0 = sqrtf(a.x*a.x + a.y*a.y + a.z*a.z);
        float bl1 = sqrtf(a.w*a.w + b.x*b.x + b.y*b.y);
        float bl2 = sqrtf(b.z*b.z + b.w*b.w + c.x*c.x);
        float bl3 = sqrtf(c.y*c.y + c.z*c.z + c.w*c.w);
        float de0 = g0*(-Ld*Ad*expf(-Ld*bl0)) - Lr*Ar*expf(-Lr*bl0);
        float de1 = g1*(-Ld*Ad*expf(-Ld*bl1)) - Lr*Ar*expf(-Lr*bl1);
        float de2 = g2*(-Ld*Ad*expf(-Ld*bl2)) - Lr*Ar*expf(-Lr*bl2);
        float de3 = g3*(-Ld*Ad*expf(-Ld*bl3)) - Lr*Ar*expf(-Lr*bl3);
        float s0 = (bl0 > 0.f) ? de0/bl0 : 0.f;
        float s1 = (bl1 > 0.f) ? de1/bl1 : 0.f;
        float s2 = (bl2 > 0.f) ? de2/bl2 : 0.f;
        float s3 = (bl3 > 0.f) ? de3/bl3 : 0.f;
        float4 o0 = { s0*a.x, s0*a.y, s0*a.z, s1*a.w };
        float4 o1 = { s1*b.x, s1*b.y, s2*b.z, s2*b.w };
        float4 o2 = { s2*c.x, s3*c.y, s3*c.z, s3*c.w };
        f4[3*q] = o0; f4[3*q+1] = o1; f4[3*q+2] = o2;
    }
    for (int e = (NQ<<2) + blockIdx.x*blockDim.x + threadIdx.x; e < E; e += stride) {
        float x = r[3*e], y = r[3*e+1], z = r[3*e+2];
        float bl = sqrtf(x*x + y*y + z*z);
        float de = g[dst[e]]*(-Ld*Ad*expf(-Ld*bl)) - Lr*Ar*expf(-Lr*bl);
        float s = (bl > 0.f) ? de/bl : 0.f;
        fvec[3*e] = s*x; fvec[3*e+1] = s*y; fvec[3*e+2] = s*z;
    }
}

__device__ __forceinline__ void fscat_pk(float* sf, int base, int d, int s,
                                         float fx, float fy, float fz) {
    unsigned ld = (unsigned)(d - base);
    if (ld < T_C) {
        pk_add(&sf[4*ld], -fx, -fy);
        atomicAdd(&sf[4*ld+2], -fz);
    }
    unsigned ls = (unsigned)(s - base);
    if (ls < T_C) {
        pk_add(&sf[4*ls],  fx,  fy);
        atomicAdd(&sf[4*ls+2],  fz);
    }
}

// K5: force scatter; [T][4] tile, pk(x,y) + scalar z: 2 ops per taken endpoint
__global__ __launch_bounds__(512) void k5_pk(
        const float* __restrict__ fvec, const int* __restrict__ src,
        const int* __restrict__ dst,
        float* __restrict__ scratch, int E, int NT, int NC)
{
    __shared__ __align__(16) float sf[T_C*4];
    int t, c;
    map_tc(blockIdx.x, NT, NC, &t, &c);
    const int base = t * T_C;
    for (int i = threadIdx.x; i < T_C*4; i += blockDim.x) sf[i] = 0.f;
    __syncthreads();
    const int NQ = E >> 2;
    const int cq = (NQ + NC - 1) / NC;
    const int q0 = c*cq;
    const int q1 = (q0 + cq < NQ) ? (q0 + cq) : NQ;
    const float4* f4 = (const float4*)fvec;
    const int4* d4 = (const int4*)dst;
    const int4* s4 = (const int4*)src;
    for (int q = q0 + (int)threadIdx.x; q < q1; q += (int)blockDim.x) {
        float4 a = f4[3*q], b = f4[3*q+1], cc = f4[3*q+2];
        int4 dd = d4[q]; int4 ss = s4[q];
        fscat_pk(sf, base, dd.x, ss.x, a.x,  a.y,  a.z);
        fscat_pk(sf, base, dd.y, ss.y, a.w,  b.x,  b.y);
        fscat_pk(sf, base, dd.z, ss.z, b.z,  b.w,  cc.x);
        fscat_pk(sf, base, dd.w, ss.w, cc.y, cc.z, cc.w);
    }
    if (c == NC-1) {
        for (int e = (NQ<<2) + (int)threadIdx.x; e < E; e += (int)blockDim.x) {
            fscat_pk(sf, base, dst[e], src[e], fvec[3*e], fvec[3*e+1], fvec[3*e+2]);
        }
    }
    __syncthreads();
    size_t sb = (size_t)(t * NC + c) * (T_C*4);
    for (int i = threadIdx.x; i < T_C*4; i += blockDim.x) scratch[sb + i] = sf[i];
}

// K6: reduce [T][4] force chunks -> forces
__global__ __launch_bounds__(256) void k6_pk(
        const float* __restrict__ scratch, float* __restrict__ forces,
        int N, int NC)
{
    int n = blockIdx.x*blockDim.x + threadIdx.x;
    if (n >= N) return;
    int t = n / T_C; int off = n - t*T_C;
    const float4* sp = (const float4*)scratch;
    size_t idx0 = (size_t)(t*NC)*T_C + off;
    float ox = 0.f, oy = 0.f, oz = 0.f;
    for (int k = 0; k < NC; ++k) {
        float4 v = sp[idx0 + (size_t)k*T_C];
        ox += v.x; oy += v.y; oz += v.z;
    }
    forces[3*n+0] = ox; forces[3*n+1] = oy; forces[3*n+2] = oz;
}

#else
// =================== NO-PK PATH (R5 fast path, proven) ===================
#define T_N 40704
#define T_F 13568
#define T_F3 (T_F*3)

__global__ __launch_bounds__(512) void k2_dens_tiles(
        const float* __restrict__ dens_arr, const int* __restrict__ dst,
        float* __restrict__ scratch, int E, int NT, int NC)
{
    __shared__ float sd[T_N];
    int t, k;
    map_tc(blockIdx.x, NT, NC, &t, &k);
    const int base = t * T_N;
    for (int i = threadIdx.x; i < T_N; i += blockDim.x) sd[i] = 0.f;
    __syncthreads();
    const int NQ = E >> 2;
    const int cq = (NQ + NC - 1) / NC;
    const int q0 = k*cq;
    const int q1 = (q0 + cq < NQ) ? (q0 + cq) : NQ;
    const float4* dens4 = (const float4*)dens_arr;
    const int4*   d4 = (const int4*)dst;
    for (int q = q0 + (int)threadIdx.x; q < q1; q += (int)blockDim.x) {
        float4 dv = dens4[q]; int4 dd = d4[q];
        unsigned l;
        l = (unsigned)(dd.x - base); if (l < T_N) atomicAdd(&sd[l], dv.x);
        l = (unsigned)(dd.y - base); if (l < T_N) atomicAdd(&sd[l], dv.y);
        l = (unsigned)(dd.z - base); if (l < T_N) atomicAdd(&sd[l], dv.z);
        l = (unsigned)(dd.w - base); if (l < T_N) atomicAdd(&sd[l], dv.w);
    }
    if (k == NC-1) {
        for (int e = (NQ<<2) + (int)threadIdx.x; e < E; e += (int)blockDim.x) {
            unsigned l = (unsigned)(dst[e] - base);
            if (l < T_N) atomicAdd(&sd[l], dens_arr[e]);
        }
    }
    __syncthreads();
    size_t sb = (size_t)(t * NC + k) * T_N;
    for (int i = threadIdx.x; i < T_N; i += blockDim.x) scratch[sb + i] = sd[i];
}

__global__ __launch_bounds__(256) void k3_node(
        const float* __restrict__ scratch, const int* __restrict__ n2g,
        const float* __restrict__ p_ea,
        float* __restrict__ g_out, float* __restrict__ e_graph, int N, int NC)
{
    __shared__ float sbin[NG];
    if (threadIdx.x < NG) sbin[threadIdx.x] = 0.f;
    __syncthreads();
    const float Ae = softplus_f(*p_ea);
    int n = blockIdx.x*blockDim.x + threadIdx.x;
    if (n < N) {
        int t = n / T_N; int off = n - t*T_N;
        const float* bp = scratch + ((size_t)t*NC)*T_N + off;
        float l = 0.f;
        for (int k = 0; k < NC; ++k) l += bp[(size_t)k*T_N];
        float s = sqrtf(fmaxf(l, 1e-12f));
        atomicAdd(&sbin[n2g[n]], -Ae*s);
        g_out[n] = (l >= 1e-12f) ? (-0.5f*Ae/s) : 0.f;
    }
    __syncthreads();
    if (threadIdx.x < NG) atomicAdd(&e_graph[threadIdx.x], sbin[threadIdx.x]);
}

__global__ __launch_bounds__(256) void k4_fvec(
        const float* __restrict__ r, const int* __restrict__ dst,
        const int* __restrict__ n2g, const float* __restrict__ g,
        const float* __restrict__ p_da, const float* __restrict__ p_dl,
        const float* __restrict__ p_ra, const float* __restrict__ p_rl,
        float* __restrict__ fvec, float* __restrict__ e_graph, int E)
{
    __shared__ float sbin[NG];
    if (threadIdx.x < NG) sbin[threadIdx.x] = 0.f;
    __syncthreads();
    const float Ad = softplus_f(*p_da), Ld = softplus_f(*p_dl);
    const float Ar = softplus_f(*p_ra), Lr = softplus_f(*p_rl);
    const float4* r4 = (const float4*)r;
    const int4*   d4 = (const int4*)dst;
    float4* f4 = (float4*)fvec;
    const int NQ = E >> 2;
    const int stride = gridDim.x * blockDim.x;
    for (int q = blockIdx.x*blockDim.x + threadIdx.x; q < NQ; q += stride) {
        float4 a = r4[3*q], b = r4[3*q+1], c = r4[3*q+2];
        int4 dd = d4[q];
        float g0 = g[dd.x], g1 = g[dd.y], g2 = g[dd.z], g3 = g[dd.w];
        int b0 = n2g[dd.x], b1 = n2g[dd.y], b2 = n2g[dd.z], b3 = n2g[dd.w];
        float bl0 = sqrtf(a.x*a.x + a.y*a.y + a.z*a.z);
        float bl1 = sqrtf(a.w*a.w + b.x*b.x + b.y*b.y);
        float bl2 = sqrtf(b.z*b.z + b.w*b.w + c.x*c.x);
        float bl3 = sqrtf(c.y*c.y + c.z*c.z + c.w*c.w);
        float rep0 = Ar*expf(-Lr*bl0), rep1 = Ar*expf(-Lr*bl1);
        float rep2 = Ar*expf(-Lr*bl2), rep3 = Ar*expf(-Lr*bl3);
        float de0 = g0*(-Ld*Ad*expf(-Ld*bl0)) - Lr*rep0;
        float de1 = g1*(-Ld*Ad*expf(-Ld*bl1)) - Lr*rep1;
        float de2 = g2*(-Ld*Ad*expf(-Ld*bl2)) - Lr*rep2;
        float de3 = g3*(-Ld*Ad*expf(-Ld*bl3)) - Lr*rep3;
        float s0 = (bl0 > 0.f) ? de0/bl0 : 0.f;
        float s1 = (bl1 > 0.f) ? de1/bl1 : 0.f;
        float s2 = (bl2 > 0.f) ? de2/bl2 : 0.f;
        float s3 = (bl3 > 0.f) ? de3/bl3 : 0.f;
        float4 o0 = { s0*a.x, s0*a.y, s0*a.z, s1*a.w };
        float4 o1 = { s1*b.x, s1*b.y, s2*b.z, s2*b.w };
        float4 o2 = { s2*c.x, s3*c.y, s3*c.z, s3*c.w };
        f4[3*q] = o0; f4[3*q+1] = o1; f4[3*q+2] = o2;
        atomicAdd(&sbin[b0], rep0);
        atomicAdd(&sbin[b1], rep1);
        atomicAdd(&sbin[b2], rep2);
        atomicAdd(&sbin[b3], rep3);
    }
    for (int e = (NQ<<2) + blockIdx.x*blockDim.x + threadIdx.x; e < E; e += stride) {
        float x = r[3*e], y = r[3*e+1], z = r[3*e+2];
        float bl = sqrtf(x*x + y*y + z*z);
        int de = dst[e];
        float rep = Ar*expf(-Lr*bl);
        float dEdb = g[de]*(-Ld*Ad*expf(-Ld*bl)) - Lr*rep;
        float s = (bl > 0.f) ? dEdb/bl : 0.f;
        fvec[3*e] = s*x; fvec[3*e+1] = s*y; fvec[3*e+2] = s*z;
        atomicAdd(&sbin[n2g[de]], rep);
    }
    __syncthreads();
    if (threadIdx.x < NG) atomicAdd(&e_graph[threadIdx.x], sbin[threadIdx.x]);
}

__device__ __forceinline__ void fscat(float* sf, int base, int d, int s,
                                      float fx, float fy, float fz) {
    unsigned ld = (unsigned)(d - base);
    if (ld < T_F) {
        atomicAdd(&sf[3*ld+0], -fx); atomicAdd(&sf[3*ld+1], -fy); atomicAdd(&sf[3*ld+2], -fz);
    }
    unsigned ls = (unsigned)(s - base);
    if (ls < T_F) {
        atomicAdd(&sf[3*ls+0],  fx); atomicAdd(&sf[3*ls+1],  fy); atomicAdd(&sf[3*ls+2],  fz);
    }
}

__global__ __launch_bounds__(512) void k5_force_tiles(
        const float* __restrict__ fvec, const int* __restrict__ src,
        const int* __restrict__ dst,
        float* __restrict__ scratch, int E, int NT, int NC)
{
    __shared__ float sf[T_F3];
    int t, c;
    map_tc(blockIdx.x, NT, NC, &t, &c);
    const int base = t * T_F;
    for (int i = threadIdx.x; i < T_F3; i += blockDim.x) sf[i] = 0.f;
    __syncthreads();
    const int NQ = E >> 2;
    const int cq = (NQ + NC - 1) / NC;
    const int q0 = c*cq;
    const int q1 = (q0 + cq < NQ) ? (q0 + cq) : NQ;
    const float4* f4 = (const float4*)fvec;
    const int4* d4 = (const int4*)dst;
    const int4* s4 = (const int4*)src;
    for (int q = q0 + (int)threadIdx.x; q < q1; q += (int)blockDim.x) {
        float4 a = f4[3*q], b = f4[3*q+1], cc = f4[3*q+2];
        int4 dd = d4[q]; int4 ss = s4[q];
        fscat(sf, base, dd.x, ss.x, a.x,  a.y,  a.z);
        fscat(sf, base, dd.y, ss.y, a.w,  b.x,  b.y);
        fscat(sf, base, dd.z, ss.z, b.z,  b.w,  cc.x);
        fscat(sf, base, dd.w, ss.w, cc.y, cc.z, cc.w);
    }
    if (c == NC-1) {
        for (int e = (NQ<<2) + (int)threadIdx.x; e < E; e += (int)blockDim.x) {
            fscat(sf, base, dst[e], src[e], fvec[3*e], fvec[3*e+1], fvec[3*e+2]);
        }
    }
    __syncthreads();
    size_t sb = (size_t)(t * NC + c) * T_F3;
    for (int i = threadIdx.x; i < T_F3; i += blockDim.x) scratch[sb + i] = sf[i];
}

__global__ __launch_bounds__(256) void k6_force_reduce(
        const float* __restrict__ scratch, float* __restrict__ forces,
        int N, int NC)
{
    int n = blockIdx.x*blockDim.x + threadIdx.x;
    if (n >= N) return;
    int t = n / T_F; int off = n - t*T_F;
    const float* bp = scratch + ((size_t)t*NC)*T_F3 + 3*off;
    float ox = 0.f, oy = 0.f, oz = 0.f;
    for (int k = 0; k < NC; ++k) {
        const float* p = bp + (size_t)k*T_F3;
        ox += p[0]; oy += p[1]; oz += p[2];
    }
    forces[3*n+0] = ox; forces[3*n+1] = oy; forces[3*n+2] = oz;
}
#endif

// ============== FALLBACK PATH (atomic kernels, any ws_size) ==============

__global__ __launch_bounds__(256) void fb_pass1(
        const float* __restrict__ r, const int* __restrict__ dst,
        const int* __restrict__ n2g,
        const float* __restrict__ p_da, const float* __restrict__ p_dl,
        const float* __restrict__ p_ra, const float* __restrict__ p_rl,
        float* __restrict__ local_density, float* __restrict__ e_graph, int E)
{
    __shared__ float sbin[NG];
    if (threadIdx.x < NG) sbin[threadIdx.x] = 0.f;
    __syncthreads();
    const float Ad = softplus_f(*p_da), Ld = softplus_f(*p_dl);
    const float Ar = softplus_f(*p_ra), Lr = softplus_f(*p_rl);
    const int stride = gridDim.x * blockDim.x;
    for (int e = blockIdx.x*blockDim.x + threadIdx.x; e < E; e += stride) {
        float x = r[3*e], y = r[3*e+1], z = r[3*e+2];
        float bl = sqrtf(x*x + y*y + z*z);
        int de = dst[e];
        atomicAdd(&local_density[de], Ad*expf(-Ld*bl));
        atomicAdd(&sbin[n2g[de]], Ar*expf(-Lr*bl));
    }
    __syncthreads();
    if (threadIdx.x < NG) atomicAdd(&e_graph[threadIdx.x], sbin[threadIdx.x]);
}

__global__ __launch_bounds__(256) void fb_pass2(
        float* __restrict__ ld_g, const int* __restrict__ n2g,
        const float* __restrict__ p_ea, float* __restrict__ e_graph, int N)
{
    __shared__ float sbin[NG];
    if (threadIdx.x < NG) sbin[threadIdx.x] = 0.f;
    __syncthreads();
    const float Ae = softplus_f(*p_ea);
    const int stride = gridDim.x * blockDim.x;
    for (int n = blockIdx.x*blockDim.x + threadIdx.x; n < N; n += stride) {
        float l = ld_g[n];
        float s = sqrtf(fmaxf(l, 1e-12f));
        atomicAdd(&sbin[n2g[n]], -Ae*s);
        ld_g[n] = (l >= 1e-12f) ? (-0.5f*Ae/s) : 0.f;
    }
    __syncthreads();
    if (threadIdx.x < NG) atomicAdd(&e_graph[threadIdx.x], sbin[threadIdx.x]);
}

__global__ __launch_bounds__(256) void fb_pass3(
        const float* __restrict__ r, const int* __restrict__ src,
        const int* __restrict__ dst, const float* __restrict__ g,
        const float* __restrict__ p_da, const float* __restrict__ p_dl,
        const float* __restrict__ p_ra, const float* __restrict__ p_rl,
        float* __restrict__ forces, int E)
{
    const float Ad = softplus_f(*p_da), Ld = softplus_f(*p_dl);
    const float Ar = softplus_f(*p_ra), Lr = softplus_f(*p_rl);
    const int stride = gridDim.x * blockDim.x;
    for (int e = blockIdx.x*blockDim.x + threadIdx.x; e < E; e += stride) {
        float x = r[3*e], y = r[3*e+1], z = r[3*e+2];
        float bl = sqrtf(x*x + y*y + z*z);
        int de = dst[e], se = src[e];
        float dEdb = g[de]*(-Ld*Ad*expf(-Ld*bl)) - Lr*Ar*expf(-Lr*bl);
        float s = (bl > 0.f) ? dEdb/bl : 0.f;
        float fx = s*x, fy = s*y, fz = s*z;
        atomicAdd(&forces[3*de+0], -fx); atomicAdd(&forces[3*de+1], -fy); atomicAdd(&forces[3*de+2], -fz);
        atomicAdd(&forces[3*se+0],  fx); atomicAdd(&forces[3*se+1],  fy); atomicAdd(&forces[3*se+2],  fz);
    }
}

extern "C" void kernel_launch(void* const* d_in, const int* in_sizes, int n_in,
                              void* d_out, int out_size, void* d_ws, size_t ws_size,
                              hipStream_t stream) {
    const float* r    = (const float*)d_in[0];
    const int*   src  = (const int*)d_in[1];
    const int*   dst  = (const int*)d_in[2];
    const int*   n2g  = (const int*)d_in[3];
    const float* p_da = (const float*)d_in[4];
    const float* p_dl = (const float*)d_in[5];
    const float* p_ra = (const float*)d_in[6];
    const float* p_rl = (const float*)d_in[7];
    const float* p_ea = (const float*)d_in[8];

    const int E = in_sizes[1];
    const int N = in_sizes[3];

    float* e_graph = (float*)d_out;
    float* forces  = (float*)d_out + NG;

    const int E4 = (E + 3) & ~3;

    const size_t wsf_n    = ws_size / 4;
    const size_t n_ld     = ((size_t)N + 63) & ~(size_t)63;
    const size_t off_edge = n_ld;
    const size_t off_scr  = off_edge + (size_t)3 * (size_t)E4;

    long avail = (long)wsf_n - (long)off_scr;

    const int NQ = E >> 2;
    int ge = (NQ + 255) / 256; if (ge > 2048) ge = 2048;

#ifdef HAS_PK_LDS
    const int NT_A = (N + T_A - 1) / T_A;   // 5
    const int NT_C = (N + T_C - 1) / T_C;   // 10
    int NC_D = 0, NC_F = 0;
    if (avail > 0) {
        long cd = avail / ((long)NT_A * (T_A*2));
        long cf = avail / ((long)NT_C * (T_C*4));
        NC_D = (int)(cd > 64 ? 64 : cd);
        NC_F = (int)(cf > 32 ? 32 : cf);
        if (NC_D >= 8) NC_D &= ~7;
        if (NC_F >= 8) NC_F &= ~7;
    }
    if (NC_D >= 1 && NC_F >= 1) {
        float* ld_g    = (float*)d_ws;
        float* edgebuf = (float*)d_ws + off_edge;   // dens[E4], later fvec[3E] AoS
        float* scratch = (float*)d_ws + off_scr;

        hipMemsetAsync(d_out, 0, NG * sizeof(float), stream);

        k1_dens<<<ge, 256, 0, stream>>>(r, p_da, p_dl, edgebuf, E);
        k2_pk<<<NT_A * NC_D, 512, 0, stream>>>(edgebuf, dst, p_da, p_dl, p_ra, p_rl,
                                               scratch, E, NT_A, NC_D);
        k3_pk<<<(N + 255) / 256, 256, 0, stream>>>(scratch, n2g, p_ea,
                                                   ld_g, e_graph, N, NC_D);
        k4_pk<<<ge, 256, 0, stream>>>(r, dst, ld_g, p_da, p_dl, p_ra, p_rl,
                                      edgebuf, E);
        k5_pk<<<NT_C * NC_F, 512, 0, stream>>>(edgebuf, src, dst,
                                               scratch, E, NT_C, NC_F);
        k6_pk<<<(N + 255) / 256, 256, 0, stream>>>(scratch, forces, N, NC_F);
        return;
    }
#else
    const int NT_D = (N + T_N - 1) / T_N;   // 3
    const int NT_F = (N + T_F - 1) / T_F;   // 8
    int NC_D = 0, NC_F = 0;
    if (avail > 0) {
        long cd = avail / ((long)NT_D * T_N);
        long cf = avail / ((long)NT_F * T_F3);
        NC_D = (int)(cd > 80 ? 80 : cd);
        NC_F = (int)(cf > 32 ? 32 : cf);
        if (NC_D >= 8) NC_D &= ~7;
        if (NC_F >= 8) NC_F &= ~7;
    }
    if (NC_D >= 1 && NC_F >= 1) {
        float* ld_g    = (float*)d_ws;
        float* edgebuf = (float*)d_ws + off_edge;
        float* scratch = (float*)d_ws + off_scr;

        hipMemsetAsync(d_out, 0, NG * sizeof(float), stream);

        k1_dens<<<ge, 256, 0, stream>>>(r, p_da, p_dl, edgebuf, E);
        k2_dens_tiles<<<NT_D * NC_D, 512, 0, stream>>>(edgebuf, dst, scratch,
                                                       E, NT_D, NC_D);
        k3_node<<<(N + 255) / 256, 256, 0, stream>>>(scratch, n2g, p_ea,
                                                     ld_g, e_graph, N, NC_D);
        k4_fvec<<<ge, 256, 0, stream>>>(r, dst, n2g, ld_g, p_da, p_dl, p_ra, p_rl,
                                        edgebuf, e_graph, E);
        k5_force_tiles<<<NT_F * NC_F, 512, 0, stream>>>(edgebuf, src, dst,
                                                        scratch, E, NT_F, NC_F);
        k6_force_reduce<<<(N + 255) / 256, 256, 0, stream>>>(scratch, forces, N, NC_F);
        return;
    }
#endif
    {
        float* ld_g = (float*)d_ws;
        hipMemsetAsync(d_out, 0, (size_t)out_size * sizeof(float), stream);
        hipMemsetAsync(d_ws, 0, (size_t)N * sizeof(float), stream);
        int geb = (E + 255) / 256; if (geb > 2048) geb = 2048;
        fb_pass1<<<geb, 256, 0, stream>>>(r, dst, n2g, p_da, p_dl, p_ra, p_rl,
                                          ld_g, e_graph, E);
        fb_pass2<<<(N + 255) / 256, 256, 0, stream>>>(ld_g, n2g, p_ea, e_graph, N);
        fb_pass3<<<geb, 256, 0, stream>>>(r, src, dst, ld_g, p_da, p_dl, p_ra, p_rl,
                                          forces, E);
    }
}

// Round 7
// 237.379 us; speedup vs baseline: 1.8615x; 1.6819x over previous
//
#include <hip/hip_runtime.h>
#include <math.h>

#define NG 32
#define T_N 40704           // density tile: 40704 floats = 159.0 KB LDS
#define T_C 20352           // force tile: 20352 packed doubles = 159.0 KB LDS

// f64 packing constants: p = rint(32 fx)*2^33 + rint(32 fy)*2^17 + fz
#define PK_Q   32.0f
#define PK_K1  8589934592.0   // 2^33
#define PK_K2  131072.0       // 2^17

__device__ __forceinline__ float softplus_f(float x) {
    return (x > 0.f) ? (x + log1pf(expf(-x))) : log1pf(expf(x));
}

__device__ __forceinline__ void lds_fadd64(double* p, double v) {
#if defined(__HIP_PLATFORM_AMD__) || defined(__AMDGCN__)
    unsafeAtomicAdd(p, v);      // ds_add_f64 on gfx90a+
#else
    atomicAdd(p, v);
#endif
}

// gid -> (tile t, chunk c) with all tiles of a chunk on one XCD (gid%8 == c%8),
// assuming round-robin workgroup->XCD dispatch. Requires NC % 8 == 0; else identity.
__device__ __forceinline__ void map_tc(int gid, int NT, int NC, int* t, int* c) {
    if ((NC & 7) == 0) {
        int x = gid & 7, s = gid >> 3;
        *t = s % NT;
        *c = (s / NT) * 8 + x;
    } else {
        *t = gid / NC;
        *c = gid - (*t) * NC;
    }
}

// K1: pure streaming map: r -> dens
__global__ __launch_bounds__(256) void k1_dens(
        const float* __restrict__ r,
        const float* __restrict__ p_da, const float* __restrict__ p_dl,
        float* __restrict__ dens_arr, int E)
{
    const float Ad = softplus_f(*p_da), Ld = softplus_f(*p_dl);
    const float4* r4 = (const float4*)r;
    float4* dens4 = (float4*)dens_arr;
    const int NQ = E >> 2;
    const int stride = gridDim.x * blockDim.x;
    for (int q = blockIdx.x*blockDim.x + threadIdx.x; q < NQ; q += stride) {
        float4 a = r4[3*q], b = r4[3*q+1], c = r4[3*q+2];
        float bl0 = sqrtf(a.x*a.x + a.y*a.y + a.z*a.z);
        float bl1 = sqrtf(a.w*a.w + b.x*b.x + b.y*b.y);
        float bl2 = sqrtf(b.z*b.z + b.w*b.w + c.x*c.x);
        float bl3 = sqrtf(c.y*c.y + c.z*c.z + c.w*c.w);
        float4 dv = { Ad*expf(-Ld*bl0), Ad*expf(-Ld*bl1),
                      Ad*expf(-Ld*bl2), Ad*expf(-Ld*bl3) };
        dens4[q] = dv;
    }
    for (int e = (NQ<<2) + blockIdx.x*blockDim.x + threadIdx.x; e < E; e += stride) {
        float x = r[3*e], y = r[3*e+1], z = r[3*e+2];
        float bl = sqrtf(x*x + y*y + z*z);
        dens_arr[e] = Ad*expf(-Ld*bl);
    }
}

// K2: density scatter into 159KB LDS node tile (R5 proven shape)
__global__ __launch_bounds__(512) void k2_dens_tiles(
        const float* __restrict__ dens_arr, const int* __restrict__ dst,
        float* __restrict__ scratch, int E, int NT, int NC)
{
    __shared__ float sd[T_N];
    int t, k;
    map_tc(blockIdx.x, NT, NC, &t, &k);
    const int base = t * T_N;
    for (int i = threadIdx.x; i < T_N; i += blockDim.x) sd[i] = 0.f;
    __syncthreads();
    const int NQ = E >> 2;
    const int cq = (NQ + NC - 1) / NC;
    const int q0 = k*cq;
    const int q1 = (q0 + cq < NQ) ? (q0 + cq) : NQ;
    const float4* dens4 = (const float4*)dens_arr;
    const int4*   d4 = (const int4*)dst;
    for (int q = q0 + (int)threadIdx.x; q < q1; q += (int)blockDim.x) {
        float4 dv = dens4[q]; int4 dd = d4[q];
        unsigned l;
        l = (unsigned)(dd.x - base); if (l < T_N) atomicAdd(&sd[l], dv.x);
        l = (unsigned)(dd.y - base); if (l < T_N) atomicAdd(&sd[l], dv.y);
        l = (unsigned)(dd.z - base); if (l < T_N) atomicAdd(&sd[l], dv.z);
        l = (unsigned)(dd.w - base); if (l < T_N) atomicAdd(&sd[l], dv.w);
    }
    if (k == NC-1) {
        for (int e = (NQ<<2) + (int)threadIdx.x; e < E; e += (int)blockDim.x) {
            unsigned l = (unsigned)(dst[e] - base);
            if (l < T_N) atomicAdd(&sd[l], dens_arr[e]);
        }
    }
    __syncthreads();
    size_t sb = (size_t)(t * NC + k) * T_N;
    for (int i = threadIdx.x; i < T_N; i += blockDim.x) scratch[sb + i] = sd[i];
}

// K3: reduce density chunks; embedding energy -> bins; g = dE/d(local_density)
__global__ __launch_bounds__(256) void k3_node(
        const float* __restrict__ scratch, const int* __restrict__ n2g,
        const float* __restrict__ p_ea,
        float* __restrict__ g_out, float* __restrict__ e_graph, int N, int NC)
{
    __shared__ float sbin[NG];
    if (threadIdx.x < NG) sbin[threadIdx.x] = 0.f;
    __syncthreads();
    const float Ae = softplus_f(*p_ea);
    int n = blockIdx.x*blockDim.x + threadIdx.x;
    if (n < N) {
        int t = n / T_N; int off = n - t*T_N;
        const float* bp = scratch + ((size_t)t*NC)*T_N + off;
        float l = 0.f;
        for (int k = 0; k < NC; ++k) l += bp[(size_t)k*T_N];
        float s = sqrtf(fmaxf(l, 1e-12f));
        atomicAdd(&sbin[n2g[n]], -Ae*s);
        g_out[n] = (l >= 1e-12f) ? (-0.5f*Ae/s) : 0.f;
    }
    __syncthreads();
    if (threadIdx.x < NG) atomicAdd(&e_graph[threadIdx.x], sbin[threadIdx.x]);
}

// K4: per-edge dE/dr (AoS, 3 float4 per quad) + repulsive per-graph bins
__global__ __launch_bounds__(256) void k4_fvec(
        const float* __restrict__ r, const int* __restrict__ dst,
        const int* __restrict__ n2g, const float* __restrict__ g,
        const float* __restrict__ p_da, const float* __restrict__ p_dl,
        const float* __restrict__ p_ra, const float* __restrict__ p_rl,
        float* __restrict__ fvec, float* __restrict__ e_graph, int E)
{
    __shared__ float sbin[NG];
    if (threadIdx.x < NG) sbin[threadIdx.x] = 0.f;
    __syncthreads();
    const float Ad = softplus_f(*p_da), Ld = softplus_f(*p_dl);
    const float Ar = softplus_f(*p_ra), Lr = softplus_f(*p_rl);
    const float4* r4 = (const float4*)r;
    const int4*   d4 = (const int4*)dst;
    float4* f4 = (float4*)fvec;
    const int NQ = E >> 2;
    const int stride = gridDim.x * blockDim.x;
    for (int q = blockIdx.x*blockDim.x + threadIdx.x; q < NQ; q += stride) {
        float4 a = r4[3*q], b = r4[3*q+1], c = r4[3*q+2];
        int4 dd = d4[q];
        float g0 = g[dd.x], g1 = g[dd.y], g2 = g[dd.z], g3 = g[dd.w];
        int b0 = n2g[dd.x], b1 = n2g[dd.y], b2 = n2g[dd.z], b3 = n2g[dd.w];
        float bl0 = sqrtf(a.x*a.x + a.y*a.y + a.z*a.z);
        float bl1 = sqrtf(a.w*a.w + b.x*b.x + b.y*b.y);
        float bl2 = sqrtf(b.z*b.z + b.w*b.w + c.x*c.x);
        float bl3 = sqrtf(c.y*c.y + c.z*c.z + c.w*c.w);
        float rep0 = Ar*expf(-Lr*bl0), rep1 = Ar*expf(-Lr*bl1);
        float rep2 = Ar*expf(-Lr*bl2), rep3 = Ar*expf(-Lr*bl3);
        float de0 = g0*(-Ld*Ad*expf(-Ld*bl0)) - Lr*rep0;
        float de1 = g1*(-Ld*Ad*expf(-Ld*bl1)) - Lr*rep1;
        float de2 = g2*(-Ld*Ad*expf(-Ld*bl2)) - Lr*rep2;
        float de3 = g3*(-Ld*Ad*expf(-Ld*bl3)) - Lr*rep3;
        float s0 = (bl0 > 0.f) ? de0/bl0 : 0.f;
        float s1 = (bl1 > 0.f) ? de1/bl1 : 0.f;
        float s2 = (bl2 > 0.f) ? de2/bl2 : 0.f;
        float s3 = (bl3 > 0.f) ? de3/bl3 : 0.f;
        float4 o0 = { s0*a.x, s0*a.y, s0*a.z, s1*a.w };
        float4 o1 = { s1*b.x, s1*b.y, s2*b.z, s2*b.w };
        float4 o2 = { s2*c.x, s3*c.y, s3*c.z, s3*c.w };
        f4[3*q] = o0; f4[3*q+1] = o1; f4[3*q+2] = o2;
        atomicAdd(&sbin[b0], rep0);
        atomicAdd(&sbin[b1], rep1);
        atomicAdd(&sbin[b2], rep2);
        atomicAdd(&sbin[b3], rep3);
    }
    for (int e = (NQ<<2) + blockIdx.x*blockDim.x + threadIdx.x; e < E; e += stride) {
        float x = r[3*e], y = r[3*e+1], z = r[3*e+2];
        float bl = sqrtf(x*x + y*y + z*z);
        int de = dst[e];
        float rep = Ar*expf(-Lr*bl);
        float dEdb = g[de]*(-Ld*Ad*expf(-Ld*bl)) - Lr*rep;
        float s = (bl > 0.f) ? dEdb/bl : 0.f;
        fvec[3*e] = s*x; fvec[3*e+1] = s*y; fvec[3*e+2] = s*z;
        atomicAdd(&sbin[n2g[de]], rep);
    }
    __syncthreads();
    if (threadIdx.x < NG) atomicAdd(&e_graph[threadIdx.x], sbin[threadIdx.x]);
}

// pack 3 force comps into one f64: rint(32x)*2^33 + rint(32y)*2^17 + z
__device__ __forceinline__ double pk3(float fx, float fy, float fz) {
    double hx = (double)rintf(fx * PK_Q);
    double hy = (double)rintf(fy * PK_Q);
    return hx * PK_K1 + hy * PK_K2 + (double)fz;
}

__device__ __forceinline__ void fscat64(double* sf, int base, int d, int s, double p) {
    unsigned ld = (unsigned)(d - base);
    if (ld < T_C) lds_fadd64(&sf[ld], -p);
    unsigned ls = (unsigned)(s - base);
    if (ls < T_C) lds_fadd64(&sf[ls],  p);
}

// K5: force scatter; ONE packed f64 LDS atomic per taken endpoint
__global__ __launch_bounds__(512) void k5_pk64(
        const float* __restrict__ fvec, const int* __restrict__ src,
        const int* __restrict__ dst,
        double* __restrict__ scratch, int E, int NT, int NC)
{
    __shared__ double sf[T_C];
    int t, c;
    map_tc(blockIdx.x, NT, NC, &t, &c);
    const int base = t * T_C;
    for (int i = threadIdx.x; i < T_C; i += blockDim.x) sf[i] = 0.0;
    __syncthreads();
    const int NQ = E >> 2;
    const int cq = (NQ + NC - 1) / NC;
    const int q0 = c*cq;
    const int q1 = (q0 + cq < NQ) ? (q0 + cq) : NQ;
    const float4* f4 = (const float4*)fvec;
    const int4* d4 = (const int4*)dst;
    const int4* s4 = (const int4*)src;
    for (int q = q0 + (int)threadIdx.x; q < q1; q += (int)blockDim.x) {
        float4 a = f4[3*q], b = f4[3*q+1], cc = f4[3*q+2];
        int4 dd = d4[q]; int4 ss = s4[q];
        double p0 = pk3(a.x,  a.y,  a.z);
        double p1 = pk3(a.w,  b.x,  b.y);
        double p2 = pk3(b.z,  b.w,  cc.x);
        double p3 = pk3(cc.y, cc.z, cc.w);
        fscat64(sf, base, dd.x, ss.x, p0);
        fscat64(sf, base, dd.y, ss.y, p1);
        fscat64(sf, base, dd.z, ss.z, p2);
        fscat64(sf, base, dd.w, ss.w, p3);
    }
    if (c == NC-1) {
        for (int e = (NQ<<2) + (int)threadIdx.x; e < E; e += (int)blockDim.x) {
            double p = pk3(fvec[3*e], fvec[3*e+1], fvec[3*e+2]);
            fscat64(sf, base, dst[e], src[e], p);
        }
    }
    __syncthreads();
    size_t sb = (size_t)(t * NC + c) * T_C;
    for (int i = threadIdx.x; i < T_C; i += blockDim.x) scratch[sb + i] = sf[i];
}

// K6: sum packed chunks, decode fields -> forces (fully overwrites output)
__global__ __launch_bounds__(256) void k6_pk64(
        const double* __restrict__ scratch, float* __restrict__ forces,
        int N, int NC)
{
    int n = blockIdx.x*blockDim.x + threadIdx.x;
    if (n >= N) return;
    int t = n / T_C; int off = n - t*T_C;
    const double* bp = scratch + ((size_t)t*NC)*T_C + off;
    double V = 0.0;
    for (int k = 0; k < NC; ++k) V += bp[(size_t)k*T_C];
    double h1 = rint(V * (1.0/PK_K1));
    double rem = V - h1 * PK_K1;
    double h2 = rint(rem * (1.0/PK_K2));
    double Z = rem - h2 * PK_K2;
    forces[3*n+0] = (float)(h1 * (1.0/(double)PK_Q));
    forces[3*n+1] = (float)(h2 * (1.0/(double)PK_Q));
    forces[3*n+2] = (float)Z;
}

// ============== FALLBACK PATH (atomic kernels, any ws_size) ==============

__global__ __launch_bounds__(256) void fb_pass1(
        const float* __restrict__ r, const int* __restrict__ dst,
        const int* __restrict__ n2g,
        const float* __restrict__ p_da, const float* __restrict__ p_dl,
        const float* __restrict__ p_ra, const float* __restrict__ p_rl,
        float* __restrict__ local_density, float* __restrict__ e_graph, int E)
{
    __shared__ float sbin[NG];
    if (threadIdx.x < NG) sbin[threadIdx.x] = 0.f;
    __syncthreads();
    const float Ad = softplus_f(*p_da), Ld = softplus_f(*p_dl);
    const float Ar = softplus_f(*p_ra), Lr = softplus_f(*p_rl);
    const int stride = gridDim.x * blockDim.x;
    for (int e = blockIdx.x*blockDim.x + threadIdx.x; e < E; e += stride) {
        float x = r[3*e], y = r[3*e+1], z = r[3*e+2];
        float bl = sqrtf(x*x + y*y + z*z);
        int de = dst[e];
        atomicAdd(&local_density[de], Ad*expf(-Ld*bl));
        atomicAdd(&sbin[n2g[de]], Ar*expf(-Lr*bl));
    }
    __syncthreads();
    if (threadIdx.x < NG) atomicAdd(&e_graph[threadIdx.x], sbin[threadIdx.x]);
}

__global__ __launch_bounds__(256) void fb_pass2(
        float* __restrict__ ld_g, const int* __restrict__ n2g,
        const float* __restrict__ p_ea, float* __restrict__ e_graph, int N)
{
    __shared__ float sbin[NG];
    if (threadIdx.x < NG) sbin[threadIdx.x] = 0.f;
    __syncthreads();
    const float Ae = softplus_f(*p_ea);
    const int stride = gridDim.x * blockDim.x;
    for (int n = blockIdx.x*blockDim.x + threadIdx.x; n < N; n += stride) {
        float l = ld_g[n];
        float s = sqrtf(fmaxf(l, 1e-12f));
        atomicAdd(&sbin[n2g[n]], -Ae*s);
        ld_g[n] = (l >= 1e-12f) ? (-0.5f*Ae/s) : 0.f;
    }
    __syncthreads();
    if (threadIdx.x < NG) atomicAdd(&e_graph[threadIdx.x], sbin[threadIdx.x]);
}

__global__ __launch_bounds__(256) void fb_pass3(
        const float* __restrict__ r, const int* __restrict__ src,
        const int* __restrict__ dst, const float* __restrict__ g,
        const float* __restrict__ p_da, const float* __restrict__ p_dl,
        const float* __restrict__ p_ra, const float* __restrict__ p_rl,
        float* __restrict__ forces, int E)
{
    const float Ad = softplus_f(*p_da), Ld = softplus_f(*p_dl);
    const float Ar = softplus_f(*p_ra), Lr = softplus_f(*p_rl);
    const int stride = gridDim.x * blockDim.x;
    for (int e = blockIdx.x*blockDim.x + threadIdx.x; e < E; e += stride) {
        float x = r[3*e], y = r[3*e+1], z = r[3*e+2];
        float bl = sqrtf(x*x + y*y + z*z);
        int de = dst[e], se = src[e];
        float dEdb = g[de]*(-Ld*Ad*expf(-Ld*bl)) - Lr*Ar*expf(-Lr*bl);
        float s = (bl > 0.f) ? dEdb/bl : 0.f;
        float fx = s*x, fy = s*y, fz = s*z;
        atomicAdd(&forces[3*de+0], -fx); atomicAdd(&forces[3*de+1], -fy); atomicAdd(&forces[3*de+2], -fz);
        atomicAdd(&forces[3*se+0],  fx); atomicAdd(&forces[3*se+1],  fy); atomicAdd(&forces[3*se+2],  fz);
    }
}

extern "C" void kernel_launch(void* const* d_in, const int* in_sizes, int n_in,
                              void* d_out, int out_size, void* d_ws, size_t ws_size,
                              hipStream_t stream) {
    const float* r    = (const float*)d_in[0];
    const int*   src  = (const int*)d_in[1];
    const int*   dst  = (const int*)d_in[2];
    const int*   n2g  = (const int*)d_in[3];
    const float* p_da = (const float*)d_in[4];
    const float* p_dl = (const float*)d_in[5];
    const float* p_ra = (const float*)d_in[6];
    const float* p_rl = (const float*)d_in[7];
    const float* p_ea = (const float*)d_in[8];

    const int E = in_sizes[1];
    const int N = in_sizes[3];

    float* e_graph = (float*)d_out;
    float* forces  = (float*)d_out + NG;

    const int E4 = (E + 3) & ~3;
    const int NT_D = (N + T_N - 1) / T_N;   // 3
    const int NT_C = (N + T_C - 1) / T_C;   // 5

    const size_t wsf_n    = ws_size / 4;
    const size_t n_ld     = ((size_t)N + 63) & ~(size_t)63;
    const size_t off_edge = n_ld;
    const size_t off_scr  = (off_edge + (size_t)3 * (size_t)E4 + 1) & ~(size_t)1; // 8B-aligned

    long avail = (long)wsf_n - (long)off_scr;
    int NC_D = 0, NC_F = 0;
    if (avail > 0) {
        long cd = avail / ((long)NT_D * T_N);        // floats per density chunk
        long cf = avail / ((long)NT_C * T_C * 2);    // floats per packed force chunk
        NC_D = (int)(cd > 80 ? 80 : cd);
        NC_F = (int)(cf > 48 ? 48 : cf);
        if (NC_D >= 8) NC_D &= ~7;
        if (NC_F >= 8) NC_F &= ~7;
    }

    const int NQ = E >> 2;
    int ge = (NQ + 255) / 256; if (ge > 2048) ge = 2048;

    if (NC_D >= 1 && NC_F >= 1) {
        float*  ld_g     = (float*)d_ws;
        float*  edgebuf  = (float*)d_ws + off_edge;   // dens[E4], later fvec[3E] AoS
        float*  scratchf = (float*)d_ws + off_scr;
        double* scratchd = (double*)scratchf;

        hipMemsetAsync(d_out, 0, NG * sizeof(float), stream);

        k1_dens<<<ge, 256, 0, stream>>>(r, p_da, p_dl, edgebuf, E);
        k2_dens_tiles<<<NT_D * NC_D, 512, 0, stream>>>(edgebuf, dst, scratchf,
                                                       E, NT_D, NC_D);
        k3_node<<<(N + 255) / 256, 256, 0, stream>>>(scratchf, n2g, p_ea,
                                                     ld_g, e_graph, N, NC_D);
        k4_fvec<<<ge, 256, 0, stream>>>(r, dst, n2g, ld_g, p_da, p_dl, p_ra, p_rl,
                                        edgebuf, e_graph, E);
        k5_pk64<<<NT_C * NC_F, 512, 0, stream>>>(edgebuf, src, dst,
                                                 scratchd, E, NT_C, NC_F);
        k6_pk64<<<(N + 255) / 256, 256, 0, stream>>>(scratchd, forces, N, NC_F);
    } else {
        float* ld_g = (float*)d_ws;
        hipMemsetAsync(d_out, 0, (size_t)out_size * sizeof(float), stream);
        hipMemsetAsync(d_ws, 0, (size_t)N * sizeof(float), stream);
        int geb = (E + 255) / 256; if (geb > 2048) geb = 2048;
        fb_pass1<<<geb, 256, 0, stream>>>(r, dst, n2g, p_da, p_dl, p_ra, p_rl,
                                          ld_g, e_graph, E);
        fb_pass2<<<(N + 255) / 256, 256, 0, stream>>>(ld_g, n2g, p_ea, e_graph, N);
        fb_pass3<<<geb, 256, 0, stream>>>(r, src, dst, ld_g, p_da, p_dl, p_ra, p_rl,
                                          forces, E);
    }
}